// Round 1
// baseline (5344.001 us; speedup 1.0000x reference)
//
#include <hip/hip_runtime.h>
#include <math.h>

// ---------------- problem dims ----------------
#define DD    1024
#define TT    128
#define BB    256
#define NE    64
#define NCC   128
#define PPP   50
#define NCK   8
#define HH    512
#define G4    2048     // 4*HH
#define NROWS 32768    // BB*TT
#define K3PAD 3200     // padded K for phase2/3 GEMMs (3123 / 3173 -> 3200)
#define CHUNK 8        // timesteps per XG chunk

// ---------------- workspace layout (float offsets) ----------------
#define F_HSEQ  0ull            // Hseq hi [32768][1024] u16 + lo (33,554,432 float-slots); later D2/CHE/D3
#define F_XG    33554432ull     // [2][CHUNK][256][2048] fp32 8,388,608 ; later H3
#define F_WIH   41943040ull     // bf16 hi[2][2048][1024] + lo  (4,194,304 float-slots)
#define F_WHH   46137344ull     // bf16 hi[2][2048][512] + lo   (2,097,152)
#define F_S1    48234496ull     // bf16 hi[1024][1024] + lo     (1,048,576)
#define F_W2    49283072ull     // bf16 hi[1024][3200] + lo     (3,276,800)
#define F_W3    52559872ull     // bf16 hi[1024][3200] + lo     (3,276,800)
#define F_BIASC 56885248ull     // [2][2048]
#define F_HST   56889344ull     // h state: hi[2par][2dir][256][512] u16 + lo  (= 524,288 float-slots)
#define F_CST   57413632ull     // [2][256][512] = 262,144
#define F_CS    57675776ull
#define F_CSQ   57676800ull
#define F_BNM   57677824ull
#define F_BNI   57678848ull
#define F_ALPHA 57679872ull     // [BB*TT]
#define F_U     57712640ull     // [BB,DD] 262,144
#define F_H2    57974784ull     // [64,8,1024] 524,288
#define F_BN2M  58499072ull
#define F_BN2I  58564608ull
#define F_EXTRA 58630144ull
#define F_BN3M  58631168ull
#define F_BN3I  58696704ull

#define F_D2    F_HSEQ
#define F_CHE   (F_HSEQ + 26214400ull)
#define F_D3    F_HSEQ
#define F_H3    F_XG
// sync counters overlay the (dead during LSTM) H2 region: 128 steps x 8 groups ints
#define F_SYNC  F_H2

typedef short s8v __attribute__((ext_vector_type(8)));
typedef float f4v __attribute__((ext_vector_type(4)));

__device__ __forceinline__ float leakyf(float x) { return x >= 0.f ? x : 0.01f * x; }
__device__ __forceinline__ float sigmf(float x)  { return 1.f / (1.f + __expf(-x)); }
__device__ __forceinline__ float tanhfast(float x) {
  float e = __expf(2.f * x);          // +inf for large x -> 1; 0 for very negative -> -1
  return 1.f - 2.f / (e + 1.f);
}

__device__ __forceinline__ float blk_sum(float v, float* s4) {
  for (int o = 32; o > 0; o >>= 1) v += __shfl_down(v, o);
  __syncthreads();
  if ((threadIdx.x & 63) == 0) s4[threadIdx.x >> 6] = v;
  __syncthreads();
  return s4[0] + s4[1] + s4[2] + s4[3];
}

// pack 2 fp32 -> (hi bf16 pair, lo bf16 pair); hi = truncation, lo = exact residual truncated
__device__ __forceinline__ void cvt2(float x0, float x1, unsigned& hi, unsigned& lo) {
  unsigned b0 = __float_as_uint(x0), b1 = __float_as_uint(x1);
  hi = (b0 >> 16) | (b1 & 0xffff0000u);
  float h0 = __uint_as_float(b0 & 0xffff0000u);
  float h1 = __uint_as_float(b1 & 0xffff0000u);
  unsigned l0 = __float_as_uint(x0 - h0);
  unsigned l1 = __float_as_uint(x1 - h1);
  lo = (l0 >> 16) | (l1 & 0xffff0000u);
}

// weight convert: src fp32 [N][Ks] row-major -> hi/lo bf16 [N][Kd] (zero-padded)
__global__ __launch_bounds__(256) void k_cvt(const float* __restrict__ src,
                                             unsigned short* __restrict__ hi,
                                             unsigned short* __restrict__ lo,
                                             int Ks, int Kd) {
  int n = blockIdx.x;
  for (int k = threadIdx.x; k < Kd; k += 256) {
    float v = (k < Ks) ? src[(size_t)n * Ks + k] : 0.f;
    unsigned b = __float_as_uint(v);
    float h = __uint_as_float(b & 0xffff0000u);
    hi[(size_t)n * Kd + k] = (unsigned short)(b >> 16);
    lo[(size_t)n * Kd + k] = (unsigned short)(__float_as_uint(v - h) >> 16);
  }
}

__global__ __launch_bounds__(256) void k_biasc(const float* __restrict__ bf1, const float* __restrict__ bf2,
                                               const float* __restrict__ bb1, const float* __restrict__ bb2,
                                               float* __restrict__ out) {
  int i = blockIdx.x * 256 + threadIdx.x;  // 4096
  if (i < G4) out[i] = bf1[i] + bf2[i];
  else        out[i] = bb1[i - G4] + bb2[i - G4];
}

// ---------------- MFMA GEMM, 128x128 tile, split-bf16 3-term (fp32-accurate) ----------------
// B bf16 hi/lo n-major [N][K].
// MODE 0 STORE: A fp32; C = A@B + bias                         (p2/p3 GEMMs)
// MODE 1 STATS: A pre-split hi/lo; atomic col sum/sumsq        (z pass 1)
// MODE 2 ALPHA: A pre-split hi/lo; atomic row sum of leaky((z-bnm)*bni)*s2w  (z pass 2)
// MODE 3 XG:    A fp32 rows gathered from X via lens; dir = blockIdx.z
template <int MODE>
__global__ __launch_bounds__(256, 2) void k_mf(
    const float* __restrict__ A,
    const unsigned short* __restrict__ Ahi, const unsigned short* __restrict__ Alo,
    const unsigned short* __restrict__ Bhi, const unsigned short* __restrict__ Blo,
    const float* __restrict__ bias, float* __restrict__ C, int M, int N, int K,
    const int* __restrict__ lens, int c,
    const float* __restrict__ bnm, const float* __restrict__ bni,
    const float* __restrict__ s2w, float* __restrict__ cs,
    float* __restrict__ csq, float* __restrict__ alpha) {
  __shared__ unsigned short Ah[128][40];
  __shared__ unsigned short Al[128][40];
  __shared__ unsigned short Bh[128][40];
  __shared__ unsigned short Bl[128][40];
  const int tid = threadIdx.x;
  const int m0 = blockIdx.x * 128;
  const int n0 = blockIdx.y * 128;
  const int dir = (MODE == 3) ? blockIdx.z : 0;

  const int sr = tid >> 1;
  const int sh = tid & 1;
  const float* arow = nullptr;
  const unsigned short* ahrow = nullptr;
  const unsigned short* alrow = nullptr;
  if (MODE == 3) {
    int tl = m0 >> 8;
    int b = (m0 & 255) + sr;
    int t = c * CHUNK + tl;
    int len = lens[b];
    int r = (dir == 0) ? t : ((t < len) ? (len - 1 - t) : t);
    arow = A + ((size_t)b * TT + r) * DD;
  } else if (MODE == 0) {
    arow = A + (size_t)(m0 + sr) * K;
  } else {
    ahrow = Ahi + (size_t)(m0 + sr) * K;
    alrow = Alo + (size_t)(m0 + sr) * K;
  }
  const unsigned short* bhrow = Bhi + ((size_t)dir * N + n0 + sr) * K;
  const unsigned short* blrow = Blo + ((size_t)dir * N + n0 + sr) * K;

  const int wave = tid >> 6, lane = tid & 63;
  const int wm = wave & 1, wn = wave >> 1;
  const int quad = lane >> 4, l15 = lane & 15;

  f4v acc[4][4];
#pragma unroll
  for (int i = 0; i < 4; ++i)
#pragma unroll
    for (int j = 0; j < 4; ++j) acc[i][j] = (f4v){0.f, 0.f, 0.f, 0.f};

#pragma unroll 1
  for (int k0 = 0; k0 < K; k0 += 32) {
    __syncthreads();
    if (MODE == 1 || MODE == 2) {
      const uint4* ph = (const uint4*)(ahrow + k0 + sh * 16);
      uint4* dh = (uint4*)&Ah[sr][sh * 16];
      dh[0] = ph[0]; dh[1] = ph[1];
      const uint4* pl = (const uint4*)(alrow + k0 + sh * 16);
      uint4* dl = (uint4*)&Al[sr][sh * 16];
      dl[0] = pl[0]; dl[1] = pl[1];
    } else {
      const float4* pa = (const float4*)(arow + k0 + sh * 16);
      float4 v0 = pa[0], v1 = pa[1], v2 = pa[2], v3 = pa[3];
      unsigned h[8], l[8];
      cvt2(v0.x, v0.y, h[0], l[0]); cvt2(v0.z, v0.w, h[1], l[1]);
      cvt2(v1.x, v1.y, h[2], l[2]); cvt2(v1.z, v1.w, h[3], l[3]);
      cvt2(v2.x, v2.y, h[4], l[4]); cvt2(v2.z, v2.w, h[5], l[5]);
      cvt2(v3.x, v3.y, h[6], l[6]); cvt2(v3.z, v3.w, h[7], l[7]);
      uint4* dh = (uint4*)&Ah[sr][sh * 16];
      dh[0] = make_uint4(h[0], h[1], h[2], h[3]);
      dh[1] = make_uint4(h[4], h[5], h[6], h[7]);
      uint4* dl = (uint4*)&Al[sr][sh * 16];
      dl[0] = make_uint4(l[0], l[1], l[2], l[3]);
      dl[1] = make_uint4(l[4], l[5], l[6], l[7]);
    }
    {
      const uint4* pbh = (const uint4*)(bhrow + k0 + sh * 16);
      uint4* dbh = (uint4*)&Bh[sr][sh * 16];
      dbh[0] = pbh[0]; dbh[1] = pbh[1];
      const uint4* pbl = (const uint4*)(blrow + k0 + sh * 16);
      uint4* dbl = (uint4*)&Bl[sr][sh * 16];
      dbl[0] = pbl[0]; dbl[1] = pbl[1];
    }
    __syncthreads();
    s8v ah[4], al[4], bh[4], bl[4];
#pragma unroll
    for (int mi = 0; mi < 4; ++mi) {
      ah[mi] = *(const s8v*)&Ah[wm * 64 + mi * 16 + l15][quad * 8];
      al[mi] = *(const s8v*)&Al[wm * 64 + mi * 16 + l15][quad * 8];
    }
#pragma unroll
    for (int ni = 0; ni < 4; ++ni) {
      bh[ni] = *(const s8v*)&Bh[wn * 64 + ni * 16 + l15][quad * 8];
      bl[ni] = *(const s8v*)&Bl[wn * 64 + ni * 16 + l15][quad * 8];
    }
#pragma unroll
    for (int mi = 0; mi < 4; ++mi)
#pragma unroll
      for (int ni = 0; ni < 4; ++ni) {
        acc[mi][ni] = __builtin_amdgcn_mfma_f32_16x16x32_bf16(ah[mi], bh[ni], acc[mi][ni], 0, 0, 0);
        acc[mi][ni] = __builtin_amdgcn_mfma_f32_16x16x32_bf16(al[mi], bh[ni], acc[mi][ni], 0, 0, 0);
        acc[mi][ni] = __builtin_amdgcn_mfma_f32_16x16x32_bf16(ah[mi], bl[ni], acc[mi][ni], 0, 0, 0);
      }
  }

  // epilogue; C/D layout: col = l15, row = quad*4 + reg
  const int rb = wm * 64;
  if (MODE == 0 || MODE == 3) {
    float* Cb;
    const float* bp = bias;
    if (MODE == 3) {
      int tl = m0 >> 8;
      Cb = C + (((size_t)dir * CHUNK + tl) * 256 + (m0 & 255)) * (size_t)N;
      bp = bias + (size_t)dir * N;
    } else {
      Cb = C + (size_t)m0 * N;
    }
#pragma unroll
    for (int mi = 0; mi < 4; ++mi)
#pragma unroll
      for (int ni = 0; ni < 4; ++ni) {
        int col = n0 + wn * 64 + ni * 16 + l15;
        float bv = bp[col];
#pragma unroll
        for (int r = 0; r < 4; ++r) {
          int row = rb + mi * 16 + quad * 4 + r;
          Cb[(size_t)row * N + col] = acc[mi][ni][r] + bv;
        }
      }
  } else if (MODE == 1) {
#pragma unroll
    for (int ni = 0; ni < 4; ++ni) {
      int col = n0 + wn * 64 + ni * 16 + l15;
      float bv = bias[col];
      float s = 0.f, q = 0.f;
#pragma unroll
      for (int mi = 0; mi < 4; ++mi)
#pragma unroll
        for (int r = 0; r < 4; ++r) {
          float z = acc[mi][ni][r] + bv;
          s += z;
          q += z * z;
        }
      s += __shfl_xor(s, 16); s += __shfl_xor(s, 32);
      q += __shfl_xor(q, 16); q += __shfl_xor(q, 32);
      if (quad == 0) {
        atomicAdd(&cs[col], s);
        atomicAdd(&csq[col], q);
      }
    }
  } else {  // MODE 2
#pragma unroll
    for (int mi = 0; mi < 4; ++mi) {
      float rv[4] = {0.f, 0.f, 0.f, 0.f};
#pragma unroll
      for (int ni = 0; ni < 4; ++ni) {
        int col = n0 + wn * 64 + ni * 16 + l15;
        float bv = bias[col], mc = bnm[col], ic = bni[col], wc = s2w[col];
#pragma unroll
        for (int r = 0; r < 4; ++r) {
          float z = acc[mi][ni][r] + bv;
          rv[r] += leakyf((z - mc) * ic) * wc;
        }
      }
#pragma unroll
      for (int r = 0; r < 4; ++r) {
        float v = rv[r];
        v += __shfl_xor(v, 1); v += __shfl_xor(v, 2);
        v += __shfl_xor(v, 4); v += __shfl_xor(v, 8);
        if (l15 == 0) atomicAdd(&alpha[m0 + rb + mi * 16 + quad * 4 + r], v);
      }
    }
  }
}

// ---------------- persistent 8-step LSTM recurrence kernel ----------------
// grid (4 m-tiles x 64b, 32 j-tiles x 16, 2 dirs) = 256 blocks; 128 KB LDS each
// -> exactly 1 block/CU on 256 CUs -> all blocks co-resident (spin-sync safe).
// Whh tile (4 gates x 16 j) x K=512, hi+lo bf16, staged ONCE into LDS
// (XOR-swizzled 16B slots: slot' = slot ^ (row&7) -> conflict-free ds_read_b128).
// h state kept as pre-split bf16 hi/lo in global (bit-identical to cvt2 split);
// A-fragments load directly global->VGPR (16B per lane), no LDS round trip.
// Inter-step sync: per-(m,dir) group of 32 j-blocks via agent-scope atomics.
__global__ __launch_bounds__(256, 1) void k_rec8(
    const unsigned short* __restrict__ Bhi, const unsigned short* __restrict__ Blo,
    const float* __restrict__ XG, const int* __restrict__ lens,
    unsigned short* __restrict__ Hsh, unsigned short* __restrict__ Hsl,
    float* __restrict__ Cst,
    unsigned short* __restrict__ Hhi, unsigned short* __restrict__ Hlo,
    int* __restrict__ syncc, int c) {
  __shared__ unsigned short Bsh[64 * 512];   // 64 KB
  __shared__ unsigned short Bsl[64 * 512];   // 64 KB
  const int tid = threadIdx.x;
  const int b0 = blockIdx.x * 64;
  const int j0 = blockIdx.y * 16;
  const int dir = blockIdx.z;
  const int grp = blockIdx.x * 2 + dir;      // 8 groups of 32 blocks (the j-tiles)

  // ---- stage Whh tile into LDS with 16B-slot XOR swizzle (one time) ----
  for (int i = tid; i < 64 * 64; i += 256) { // 64 rows x 64 uint4-slots
    int row = i >> 6, s = i & 63;
    int sp = s ^ (row & 7);
    int grow = dir * G4 + (row >> 4) * HH + j0 + (row & 15);  // gate*512 + j
    ((uint4*)Bsh)[row * 64 + sp] = ((const uint4*)(Bhi + (size_t)grow * HH))[s];
    ((uint4*)Bsl)[row * 64 + sp] = ((const uint4*)(Blo + (size_t)grow * HH))[s];
  }

  const int wave = tid >> 6, lane = tid & 63;
  const int quad = lane >> 4, l15 = lane & 15;
  const int j = j0 + l15;
  const int amrow = b0 + wave * 16 + l15;    // A-frag row this lane reads

  // per-thread persistent state for its 4 output rows
  int bv[4], lenv[4];
  size_t sidx[4];
  float cstate[4];
  unsigned short hhr[4], hlr[4];
#pragma unroll
  for (int r = 0; r < 4; ++r) {
    bv[r] = b0 + wave * 16 + quad * 4 + r;
    lenv[r] = lens[bv[r]];
    sidx[r] = ((size_t)dir * BB + bv[r]) * HH + j;
    cstate[r] = Cst[sidx[r]];
  }
  {
    // chunk starts at t = c*8 (even) -> read parity 0
    size_t pbase = ((size_t)dir * BB) * HH;
#pragma unroll
    for (int r = 0; r < 4; ++r) {
      size_t idx = pbase + (size_t)bv[r] * HH + j;
      hhr[r] = Hsh[idx];
      hlr[r] = Hsl[idx];
    }
  }
  __syncthreads();   // LDS B tile ready

  for (int tt = 0; tt < CHUNK; ++tt) {
    const int t = c * CHUNK + tt;
    const int rpar = t & 1, wpar = (t + 1) & 1;

    if (tt > 0) {
      if (tid == 0) {
        while (__hip_atomic_load(syncc + (size_t)(t - 1) * 8 + grp,
                                 __ATOMIC_RELAXED, __HIP_MEMORY_SCOPE_AGENT) < 32) {
          __builtin_amdgcn_s_sleep(1);
        }
        __threadfence();   // agent acquire: invalidate so we see other XCDs' h writes
      }
      __syncthreads();
    }

    // hoisted epilogue inputs (overlap with K-loop)
    float xgv[4][4];
#pragma unroll
    for (int r = 0; r < 4; ++r) {
      size_t xgb = (((size_t)dir * CHUNK + tt) * BB + bv[r]) * (size_t)G4 + j;
#pragma unroll
      for (int g = 0; g < 4; ++g) xgv[r][g] = XG[xgb + (size_t)g * HH];
    }

    const unsigned short* arh = Hsh + (((size_t)rpar * 2 + dir) * BB + amrow) * HH;
    const unsigned short* arl = Hsl + (((size_t)rpar * 2 + dir) * BB + amrow) * HH;

    f4v acc[4];
#pragma unroll
    for (int g = 0; g < 4; ++g) acc[g] = (f4v){0.f, 0.f, 0.f, 0.f};

#pragma unroll
    for (int ks = 0; ks < 16; ++ks) {
      uint4 ch = *(const uint4*)(arh + ks * 32 + quad * 8);
      uint4 cl = *(const uint4*)(arl + ks * 32 + quad * 8);
      s8v ah = *(s8v*)&ch;
      s8v al = *(s8v*)&cl;
#pragma unroll
      for (int g = 0; g < 4; ++g) {
        int row = g * 16 + l15;
        int sp = (ks * 4 + quad) ^ (l15 & 7);    // row&7 == l15&7
        s8v bh = *(const s8v*)(Bsh + row * 512 + sp * 8);
        s8v bl = *(const s8v*)(Bsl + row * 512 + sp * 8);
        acc[g] = __builtin_amdgcn_mfma_f32_16x16x32_bf16(ah, bh, acc[g], 0, 0, 0);
        acc[g] = __builtin_amdgcn_mfma_f32_16x16x32_bf16(al, bh, acc[g], 0, 0, 0);
        acc[g] = __builtin_amdgcn_mfma_f32_16x16x32_bf16(ah, bl, acc[g], 0, 0, 0);
      }
    }

    // epilogue: cell update in registers; h split stored to write-parity buffer
    size_t wbase = (((size_t)wpar * 2 + dir) * BB) * HH;
#pragma unroll
    for (int r = 0; r < 4; ++r) {
      if (t < lenv[r]) {
        float gi = acc[0][r] + xgv[r][0];
        float gf = acc[1][r] + xgv[r][1];
        float gg = acc[2][r] + xgv[r][2];
        float go = acc[3][r] + xgv[r][3];
        float cn = sigmf(gf) * cstate[r] + sigmf(gi) * tanhfast(gg);
        float hn = sigmf(go) * tanhfast(cn);
        cstate[r] = cn;
        unsigned hb = __float_as_uint(hn);
        unsigned short h16 = (unsigned short)(hb >> 16);
        unsigned short l16 =
            (unsigned short)(__float_as_uint(hn - __uint_as_float(hb & 0xffff0000u)) >> 16);
        hhr[r] = h16;
        hlr[r] = l16;
        int ro = dir ? (lenv[r] - 1 - t) : t;
        size_t hidx = ((size_t)bv[r] * TT + ro) * DD + (size_t)dir * HH + j;
        Hhi[hidx] = h16;
        Hlo[hidx] = l16;
      }
      size_t wi = wbase + (size_t)bv[r] * HH + j;
      Hsh[wi] = hhr[r];   // masked rows: frozen value copied through
      Hsl[wi] = hlr[r];
    }

    if (tt < CHUNK - 1) {
      __syncthreads();                 // all stores issued + drained (vmcnt before barrier)
      if (tid == 0) {
        __threadfence();               // agent release: write back L2 to coherent point
        __hip_atomic_fetch_add(syncc + (size_t)t * 8 + grp, 1,
                               __ATOMIC_RELAXED, __HIP_MEMORY_SCOPE_AGENT);
      }
    }
  }

  // persist cell state for next chunk
#pragma unroll
  for (int r = 0; r < 4; ++r) Cst[sidx[r]] = cstate[r];
}

__global__ __launch_bounds__(256) void k_bnfinal(const float* __restrict__ cs, const float* __restrict__ csq,
                                                 float* __restrict__ bnm, float* __restrict__ bni, float invN) {
  int i = blockIdx.x * 256 + threadIdx.x;
  if (i < DD) {
    float m = cs[i] * invN;
    float v = csq[i] * invN - m * m;
    bnm[i] = m;
    bni[i] = rsqrtf(v + 1e-5f);
  }
}

__global__ __launch_bounds__(128) void k_asum(float* __restrict__ alpha, const int* __restrict__ lens) {
  int b = blockIdx.x;
  int t = threadIdx.x;
  int len = lens[b];
  float v = (t < len) ? alpha[b * TT + t] : 0.f;
  float s = v;
  for (int o = 32; o > 0; o >>= 1) s += __shfl_down(s, o);
  __shared__ float sw[2];
  if ((t & 63) == 0) sw[t >> 6] = s;
  __syncthreads();
  float S = sw[0] + sw[1] + 1e-9f;
  alpha[b * TT + t] = v / S;
}

__global__ __launch_bounds__(256) void k_U(const unsigned short* __restrict__ Hhi,
                                           const unsigned short* __restrict__ Hlo,
                                           const float* __restrict__ alpha,
                                           float* __restrict__ U) {
  int b = blockIdx.x;
  int tid = threadIdx.x;
  __shared__ float al[TT];
  if (tid < TT) al[tid] = alpha[b * TT + tid];
  __syncthreads();
  float4 s = make_float4(0.f, 0.f, 0.f, 0.f);
  size_t base = (size_t)b * TT * DD + tid * 4;
#pragma unroll 4
  for (int t = 0; t < TT; ++t) {
    float a = al[t];
    ushort4 hv = *(const ushort4*)(Hhi + base + (size_t)t * DD);
    ushort4 lv = *(const ushort4*)(Hlo + base + (size_t)t * DD);
    s.x += a * (__uint_as_float((unsigned)hv.x << 16) + __uint_as_float((unsigned)lv.x << 16));
    s.y += a * (__uint_as_float((unsigned)hv.y << 16) + __uint_as_float((unsigned)lv.y << 16));
    s.z += a * (__uint_as_float((unsigned)hv.z << 16) + __uint_as_float((unsigned)lv.z << 16));
    s.w += a * (__uint_as_float((unsigned)hv.w << 16) + __uint_as_float((unsigned)lv.w << 16));
  }
  *(float4*)(U + (size_t)b * DD + tid * 4) = s;
}

__global__ __launch_bounds__(256) void k_p2a(const float* __restrict__ U,
                                             const int* __restrict__ emoI,
                                             const int* __restrict__ cauI,
                                             float* __restrict__ chunkEmb) {
  int e = blockIdx.x;
  int tid = threadIdx.x;
  __shared__ float emoS[DD];
  __shared__ float sc[NCK][16];
  const float* Ue = U + (size_t)emoI[e] * DD;
  for (int i = tid; i < DD; i += 256) emoS[i] = Ue[i];
  __syncthreads();
  int w = tid >> 6, lane = tid & 63;
  for (int p = w; p < 128; p += 4) {
    const float* y = U + (size_t)cauI[p] * DD;
    float s = 0;
    for (int d = lane; d < DD; d += 64) s += emoS[d] * y[d];
    for (int o = 32; o > 0; o >>= 1) s += __shfl_down(s, o);
    if (lane == 0) sc[p >> 4][p & 15] = s;
  }
  __syncthreads();
  if (tid < NCK) {
    float mx = -1e30f;
    for (int c = 0; c < 16; ++c) mx = fmaxf(mx, sc[tid][c]);
    float sum = 0;
    for (int c = 0; c < 16; ++c) {
      float ev = __expf(sc[tid][c] - mx);
      sc[tid][c] = ev;
      sum += ev;
    }
    float inv = 1.f / sum;
    for (int c = 0; c < 16; ++c) sc[tid][c] *= inv;
  }
  __syncthreads();
  int d = tid * 4;
  for (int nn = 0; nn < NCK; ++nn) {
    float4 s = make_float4(0.f, 0.f, 0.f, 0.f);
    for (int c = 0; c < 16; ++c) {
      float wc = sc[nn][c];
      float4 y = *(const float4*)(U + (size_t)cauI[nn * 16 + c] * DD + d);
      s.x += wc * y.x; s.y += wc * y.y; s.z += wc * y.z; s.w += wc * y.w;
    }
    *(float4*)(chunkEmb + ((size_t)e * NCK + nn) * DD + d) = s;
  }
}

__global__ __launch_bounds__(256) void k_delta2(const float* __restrict__ U,
                                                const int* __restrict__ emoI,
                                                const float* __restrict__ chunkEmb,
                                                const float* __restrict__ pos,
                                                float* __restrict__ delta2) {
  int e = blockIdx.x >> 3, nn = blockIdx.x & 7;
  int tid = threadIdx.x;
  const float* emo = U + (size_t)emoI[e] * DD;
  const float* y = chunkEmb + ((size_t)e * NCK + nn) * DD;
  __shared__ float s4[4];
  float ds = 0;
  for (int d = tid; d < DD; d += 256) {
    float df = emo[d] - y[d];
    ds += df * df;
  }
  float dist = sqrtf(blk_sum(ds, s4));
  float* out = delta2 + ((size_t)e * NCK + nn) * K3PAD;
  for (int c = tid; c < K3PAD; c += 256) {
    float v;
    if (c < 1024) v = emo[c];
    else if (c < 2048) v = y[c - 1024];
    else if (c == 2048) v = dist;
    else if (c < 3073) { int d = c - 2049; v = emo[d] * y[d]; }
    else if (c < 3123) v = pos[((size_t)e * NCK + nn) * PPP + (c - 3073)];
    else v = 0.f;
    out[c] = v;
  }
}

__global__ __launch_bounds__(256) void k_bnstats(const float* __restrict__ X,
                                                 float* __restrict__ bm, float* __restrict__ bi, int R) {
  int gid = blockIdx.x * 256 + threadIdx.x;  // NE*DD
  int e = gid >> 10, col = gid & 1023;
  const float* p = X + (size_t)e * R * DD + col;
  float s = 0, s2 = 0;
  for (int r = 0; r < R; ++r) {
    float v = p[(size_t)r * DD];
    s += v;
    s2 += v * v;
  }
  float m = s / R;
  float var = s2 / R - m * m;
  bm[gid] = m;
  bi[gid] = rsqrtf(var + 1e-5f);
}

__global__ __launch_bounds__(256) void k_out2(const float* __restrict__ h2,
                                              const float* __restrict__ bm, const float* __restrict__ bi,
                                              const float* __restrict__ Wo, const float* __restrict__ Wob,
                                              float* __restrict__ out, float* __restrict__ extraf) {
  int e = blockIdx.x >> 3, nn = blockIdx.x & 7;
  int tid = threadIdx.x;
  const float* row = h2 + ((size_t)e * NCK + nn) * DD;
  float l0 = 0, l1 = 0;
  for (int col = tid; col < DD; col += 256) {
    float h = leakyf((row[col] - bm[e * DD + col]) * bi[e * DD + col]);
    l0 += h * Wo[col];
    l1 += h * Wo[DD + col];
  }
  __shared__ float s4[4];
  l0 = blk_sum(l0, s4);
  l1 = blk_sum(l1, s4);
  if (tid == 0) {
    l0 += Wob[0];
    l1 += Wob[1];
    float mx = fmaxf(l0, l1);
    float lse = mx + logf(__expf(l0 - mx) + __expf(l1 - mx));
    out[((size_t)e * NCK + nn) * 2 + 0] = l0 - lse;
    out[((size_t)e * NCK + nn) * 2 + 1] = l1 - lse;
    extraf[e * NCK + nn] = (l1 > l0) ? 1.f : 0.f;
  }
}

__global__ __launch_bounds__(256) void k_delta3(const float* __restrict__ U,
                                                const int* __restrict__ emoI,
                                                const int* __restrict__ cauI,
                                                const float* __restrict__ dis,
                                                const float* __restrict__ extraf,
                                                float* __restrict__ delta3) {
  int e = blockIdx.x >> 7, c = blockIdx.x & 127;
  int tid = threadIdx.x;
  const float* emo = U + (size_t)emoI[e] * DD;
  const float* y = U + (size_t)cauI[c] * DD;
  __shared__ float s4[4];
  float ds = 0;
  for (int d = tid; d < DD; d += 256) {
    float df = emo[d] - y[d];
    ds += df * df;
  }
  float dist = sqrtf(blk_sum(ds, s4));
  float ex = extraf[e * NCK + (c >> 4)];
  float* out = delta3 + ((size_t)e * NCC + c) * K3PAD;
  for (int col = tid; col < K3PAD; col += 256) {
    float v;
    if (col < 1024) v = emo[col];
    else if (col < 2048) v = y[col - 1024];
    else if (col == 2048) v = dist;
    else if (col < 3073) { int d = col - 2049; v = emo[d] * y[d]; }
    else if (col < 3123) v = dis[((size_t)e * NCC + c) * PPP + (col - 3073)];
    else if (col < 3173) v = ex;
    else v = 0.f;
    out[col] = v;
  }
}

__global__ __launch_bounds__(256) void k_p3(const float* __restrict__ h3,
                                            const float* __restrict__ bm, const float* __restrict__ bi,
                                            const float* __restrict__ cw, const float* __restrict__ cb,
                                            float* __restrict__ out) {
  int e = blockIdx.x >> 7, c = blockIdx.x & 127;
  int tid = threadIdx.x;
  const float* row = h3 + ((size_t)e * NCC + c) * DD;
  float l0 = 0, l1 = 0;
  for (int col = tid; col < DD; col += 256) {
    float h = leakyf((row[col] - bm[e * DD + col]) * bi[e * DD + col]);
    l0 += h * cw[col];
    l1 += h * cw[DD + col];
  }
  __shared__ float s4[4];
  l0 = blk_sum(l0, s4);
  l1 = blk_sum(l1, s4);
  if (tid == 0) {
    l0 += cb[0];
    l1 += cb[1];
    float mx = fmaxf(l0, l1);
    float lse = mx + logf(__expf(l0 - mx) + __expf(l1 - mx));
    out[((size_t)e * NCC + c) * 2 + 0] = l0 - lse;
    out[((size_t)e * NCC + c) * 2 + 1] = l1 - lse;
  }
}

__global__ __launch_bounds__(256) void k_L(const int* __restrict__ lab, float* __restrict__ out) {
  int i = blockIdx.x * 256 + threadIdx.x;  // 8192
  int e = i >> 7, c = i & 127;
  int a = lab[e * 3 + 0], b = lab[e * 3 + 1], d = lab[e * 3 + 2];
  out[i] = (a == c || b == c || d == c) ? 1.f : 0.f;
}

extern "C" void kernel_launch(void* const* d_in, const int* in_sizes, int n_in,
                              void* d_out, int out_size, void* d_ws, size_t ws_size,
                              hipStream_t stream) {
  (void)in_sizes; (void)n_in; (void)out_size; (void)ws_size;
  const float* X     = (const float*)d_in[0];
  const float* pos   = (const float*)d_in[1];
  const float* dis   = (const float*)d_in[2];
  const int*   lens  = (const int*)d_in[3];
  const int*   lab3  = (const int*)d_in[4];
  const int*   emoI  = (const int*)d_in[5];
  const int*   cauI  = (const int*)d_in[6];
  const float* Wih_f = (const float*)d_in[7];
  const float* Whh_f = (const float*)d_in[8];
  const float* bih_f = (const float*)d_in[9];
  const float* bhh_f = (const float*)d_in[10];
  const float* Wih_b = (const float*)d_in[11];
  const float* Whh_b = (const float*)d_in[12];
  const float* bih_b = (const float*)d_in[13];
  const float* bhh_b = (const float*)d_in[14];
  const float* s1w   = (const float*)d_in[15];
  const float* s1b   = (const float*)d_in[16];
  const float* s2w   = (const float*)d_in[17];
  const float* W2w   = (const float*)d_in[18];
  const float* W2b   = (const float*)d_in[19];
  const float* Wow   = (const float*)d_in[20];
  const float* Wob   = (const float*)d_in[21];
  const float* W3w   = (const float*)d_in[22];
  const float* W3b   = (const float*)d_in[23];
  const float* clsw  = (const float*)d_in[24];
  const float* clsb  = (const float*)d_in[25];
  float* ws = (float*)d_ws;
  float* out = (float*)d_out;

  unsigned short* Hhi = (unsigned short*)(ws + F_HSEQ);
  unsigned short* Hlo = Hhi + (size_t)NROWS * DD;
  unsigned short* WIHhi = (unsigned short*)(ws + F_WIH);
  unsigned short* WIHlo = WIHhi + (size_t)2 * 2048 * 1024;
  unsigned short* WHHhi = (unsigned short*)(ws + F_WHH);
  unsigned short* WHHlo = WHHhi + (size_t)2 * 2048 * 512;
  unsigned short* S1hi  = (unsigned short*)(ws + F_S1);
  unsigned short* S1lo  = S1hi + (size_t)1024 * 1024;
  unsigned short* W2hi  = (unsigned short*)(ws + F_W2);
  unsigned short* W2lo  = W2hi + (size_t)1024 * K3PAD;
  unsigned short* W3hi  = (unsigned short*)(ws + F_W3);
  unsigned short* W3lo  = W3hi + (size_t)1024 * K3PAD;
  unsigned short* Hsh   = (unsigned short*)(ws + F_HST);             // [2par][2dir][256][512]
  unsigned short* Hsl   = Hsh + (size_t)2 * 2 * BB * HH;

  // zero-init read-before-write buffers (padded Hseq rows MUST be 0 for BN stats)
  hipMemsetAsync(ws + F_HSEQ, 0, (size_t)33554432 * sizeof(float), stream);  // Hhi+Hlo
  hipMemsetAsync(ws + F_HST, 0, (size_t)(524288 + 262144) * sizeof(float), stream);  // Hsh/Hsl + CST
  hipMemsetAsync(ws + F_CS, 0, (size_t)2048 * sizeof(float), stream);                // CS + CSQ
  hipMemsetAsync(ws + F_ALPHA, 0, (size_t)32768 * sizeof(float), stream);
  hipMemsetAsync(ws + F_SYNC, 0, 4096, stream);                                      // rec sync counters

  // weight converts (fp32 -> bf16 hi/lo, n-major = native torch layout)
  k_cvt<<<2048, 256, 0, stream>>>(Wih_f, WIHhi, WIHlo, 1024, 1024);
  k_cvt<<<2048, 256, 0, stream>>>(Wih_b, WIHhi + (size_t)2048 * 1024, WIHlo + (size_t)2048 * 1024, 1024, 1024);
  k_cvt<<<2048, 256, 0, stream>>>(Whh_f, WHHhi, WHHlo, 512, 512);
  k_cvt<<<2048, 256, 0, stream>>>(Whh_b, WHHhi + (size_t)2048 * 512, WHHlo + (size_t)2048 * 512, 512, 512);
  k_cvt<<<1024, 256, 0, stream>>>(s1w, S1hi, S1lo, 1024, 1024);
  k_cvt<<<1024, 256, 0, stream>>>(W2w, W2hi, W2lo, 3123, K3PAD);
  k_cvt<<<1024, 256, 0, stream>>>(W3w, W3hi, W3lo, 3173, K3PAD);
  k_biasc<<<16, 256, 0, stream>>>(bih_f, bhh_f, bih_b, bhh_b, ws + F_BIASC);

  // BiLSTM: chunked input-projection MFMA GEMMs + persistent 8-step recurrence kernel
  for (int c = 0; c < TT / CHUNK; ++c) {
    k_mf<3><<<dim3(16, 16, 2), 256, 0, stream>>>(X, nullptr, nullptr, WIHhi, WIHlo,
                                                 ws + F_BIASC, ws + F_XG,
                                                 2048, 2048, 1024, lens, c,
                                                 nullptr, nullptr, nullptr, nullptr, nullptr, nullptr);
    k_rec8<<<dim3(4, 32, 2), 256, 0, stream>>>(WHHhi, WHHlo, ws + F_XG, lens,
                                               Hsh, Hsl, ws + F_CST, Hhi, Hlo,
                                               (int*)(ws + F_SYNC), c);
  }

  // attention: two-pass z (BN stats, then masked-linear attention weights); A pre-split
  k_mf<1><<<dim3(256, 8), 256, 0, stream>>>(nullptr, Hhi, Hlo, S1hi, S1lo, s1b, nullptr,
                                            NROWS, 1024, 1024, nullptr, 0,
                                            nullptr, nullptr, nullptr,
                                            ws + F_CS, ws + F_CSQ, nullptr);
  k_bnfinal<<<4, 256, 0, stream>>>(ws + F_CS, ws + F_CSQ, ws + F_BNM, ws + F_BNI, 1.f / NROWS);
  k_mf<2><<<dim3(256, 8), 256, 0, stream>>>(nullptr, Hhi, Hlo, S1hi, S1lo, s1b, nullptr,
                                            NROWS, 1024, 1024, nullptr, 0,
                                            ws + F_BNM, ws + F_BNI, s2w,
                                            nullptr, nullptr, ws + F_ALPHA);
  k_asum<<<BB, TT, 0, stream>>>(ws + F_ALPHA, lens);
  k_U<<<BB, 256, 0, stream>>>(Hhi, Hlo, ws + F_ALPHA, ws + F_U);

  // phase 2 (D2/CHE overlay dead Hseq region)
  k_p2a<<<NE, 256, 0, stream>>>(ws + F_U, emoI, cauI, ws + F_CHE);
  k_delta2<<<NE * NCK, 256, 0, stream>>>(ws + F_U, emoI, ws + F_CHE, pos, ws + F_D2);
  k_mf<0><<<dim3(4, 8), 256, 0, stream>>>(ws + F_D2, nullptr, nullptr, W2hi, W2lo, W2b, ws + F_H2,
                                          512, 1024, K3PAD, nullptr, 0,
                                          nullptr, nullptr, nullptr, nullptr, nullptr, nullptr);
  k_bnstats<<<256, 256, 0, stream>>>(ws + F_H2, ws + F_BN2M, ws + F_BN2I, NCK);
  k_out2<<<NE * NCK, 256, 0, stream>>>(ws + F_H2, ws + F_BN2M, ws + F_BN2I, Wow, Wob,
                                       out, ws + F_EXTRA);

  // phase 3 (D3 overlays Hseq; H3 overlays dead XG)
  k_delta3<<<NE * NCC, 256, 0, stream>>>(ws + F_U, emoI, cauI, dis, ws + F_EXTRA, ws + F_D3);
  k_mf<0><<<dim3(64, 8), 256, 0, stream>>>(ws + F_D3, nullptr, nullptr, W3hi, W3lo, W3b, ws + F_H3,
                                           8192, 1024, K3PAD, nullptr, 0,
                                           nullptr, nullptr, nullptr, nullptr, nullptr, nullptr);
  k_bnstats<<<256, 256, 0, stream>>>(ws + F_H3, ws + F_BN3M, ws + F_BN3I, NCC);
  k_p3<<<NE * NCC, 256, 0, stream>>>(ws + F_H3, ws + F_BN3M, ws + F_BN3I, clsw, clsb, out + 1024);
  k_L<<<32, 256, 0, stream>>>(lab3, out + 17408);
}

// Round 2
// 4262.766 us; speedup vs baseline: 1.2536x; 1.2536x over previous
//
#include <hip/hip_runtime.h>
#include <math.h>

// ---------------- problem dims ----------------
#define DD    1024
#define TT    128
#define BB    256
#define NE    64
#define NCC   128
#define PPP   50
#define NCK   8
#define HH    512
#define G4    2048     // 4*HH
#define NROWS 32768    // BB*TT
#define K3PAD 3200     // padded K for phase2/3 GEMMs (3123 / 3173 -> 3200)
#define CHUNK 8        // timesteps per XG chunk

// ---------------- workspace layout (float offsets) ----------------
#define F_HSEQ  0ull            // Hseq hi [32768][1024] u16 + lo (33,554,432 float-slots); later D2/CHE/D3
#define F_XG    33554432ull     // [2][CHUNK][256][2048] fp32 8,388,608 ; later H3
#define F_WIH   41943040ull     // bf16 hi[2][2048][1024] + lo  (4,194,304 float-slots)
#define F_WHH   46137344ull     // bf16 hi[2][2048][512] + lo   (2,097,152)
#define F_S1    48234496ull     // bf16 hi[1024][1024] + lo     (1,048,576)
#define F_W2    49283072ull     // bf16 hi[1024][3200] + lo     (3,276,800)
#define F_W3    52559872ull     // bf16 hi[1024][3200] + lo     (3,276,800)
#define F_BIASC 56885248ull     // [2][2048]
#define F_HST   56889344ull     // packed h state [2par][2dir][256][64oct][16] u16 = 524,288 float-slots
#define F_CST   57413632ull     // [2][256][512] = 262,144
#define F_CS    57675776ull
#define F_CSQ   57676800ull
#define F_BNM   57677824ull
#define F_BNI   57678848ull
#define F_ALPHA 57679872ull     // [BB*TT]
#define F_U     57712640ull     // [BB,DD] 262,144
#define F_H2    57974784ull     // [64,8,1024] 524,288
#define F_BN2M  58499072ull
#define F_BN2I  58564608ull
#define F_EXTRA 58630144ull
#define F_BN3M  58631168ull
#define F_BN3I  58696704ull

#define F_D2    F_HSEQ
#define F_CHE   (F_HSEQ + 26214400ull)
#define F_D3    F_HSEQ
#define F_H3    F_XG

typedef short s8v __attribute__((ext_vector_type(8)));
typedef float f4v __attribute__((ext_vector_type(4)));

__device__ __forceinline__ float leakyf(float x) { return x >= 0.f ? x : 0.01f * x; }
__device__ __forceinline__ float sigmf(float x)  { return 1.f / (1.f + __expf(-x)); }
__device__ __forceinline__ float tanhfast(float x) {
  float e = __expf(2.f * x);          // +inf for large x -> 1; 0 for very negative -> -1
  return 1.f - 2.f / (e + 1.f);
}

__device__ __forceinline__ float blk_sum(float v, float* s4) {
  for (int o = 32; o > 0; o >>= 1) v += __shfl_down(v, o);
  __syncthreads();
  if ((threadIdx.x & 63) == 0) s4[threadIdx.x >> 6] = v;
  __syncthreads();
  return s4[0] + s4[1] + s4[2] + s4[3];
}

// pack 2 fp32 -> (hi bf16 pair, lo bf16 pair); hi = truncation, lo = exact residual truncated
__device__ __forceinline__ void cvt2(float x0, float x1, unsigned& hi, unsigned& lo) {
  unsigned b0 = __float_as_uint(x0), b1 = __float_as_uint(x1);
  hi = (b0 >> 16) | (b1 & 0xffff0000u);
  float h0 = __uint_as_float(b0 & 0xffff0000u);
  float h1 = __uint_as_float(b1 & 0xffff0000u);
  unsigned l0 = __float_as_uint(x0 - h0);
  unsigned l1 = __float_as_uint(x1 - h1);
  lo = (l0 >> 16) | (l1 & 0xffff0000u);
}

// weight convert: src fp32 [N][Ks] row-major -> hi/lo bf16 [N][Kd] (zero-padded)
__global__ __launch_bounds__(256) void k_cvt(const float* __restrict__ src,
                                             unsigned short* __restrict__ hi,
                                             unsigned short* __restrict__ lo,
                                             int Ks, int Kd) {
  int n = blockIdx.x;
  for (int k = threadIdx.x; k < Kd; k += 256) {
    float v = (k < Ks) ? src[(size_t)n * Ks + k] : 0.f;
    unsigned b = __float_as_uint(v);
    float h = __uint_as_float(b & 0xffff0000u);
    hi[(size_t)n * Kd + k] = (unsigned short)(b >> 16);
    lo[(size_t)n * Kd + k] = (unsigned short)(__float_as_uint(v - h) >> 16);
  }
}

__global__ __launch_bounds__(256) void k_biasc(const float* __restrict__ bf1, const float* __restrict__ bf2,
                                               const float* __restrict__ bb1, const float* __restrict__ bb2,
                                               float* __restrict__ out) {
  int i = blockIdx.x * 256 + threadIdx.x;  // 4096
  if (i < G4) out[i] = bf1[i] + bf2[i];
  else        out[i] = bb1[i - G4] + bb2[i - G4];
}

// ---------------- MFMA GEMM, 128x128 tile, split-bf16 3-term (fp32-accurate) ----------------
// B bf16 hi/lo n-major [N][K].
// MODE 0 STORE: A fp32; C = A@B + bias                         (p2/p3 GEMMs)
// MODE 1 STATS: A pre-split hi/lo; atomic col sum/sumsq        (z pass 1)
// MODE 2 ALPHA: A pre-split hi/lo; atomic row sum of leaky((z-bnm)*bni)*s2w  (z pass 2)
// MODE 3 XG:    A fp32 rows gathered from X via lens; dir = blockIdx.z
template <int MODE>
__global__ __launch_bounds__(256, 2) void k_mf(
    const float* __restrict__ A,
    const unsigned short* __restrict__ Ahi, const unsigned short* __restrict__ Alo,
    const unsigned short* __restrict__ Bhi, const unsigned short* __restrict__ Blo,
    const float* __restrict__ bias, float* __restrict__ C, int M, int N, int K,
    const int* __restrict__ lens, int c,
    const float* __restrict__ bnm, const float* __restrict__ bni,
    const float* __restrict__ s2w, float* __restrict__ cs,
    float* __restrict__ csq, float* __restrict__ alpha) {
  __shared__ unsigned short Ah[128][40];
  __shared__ unsigned short Al[128][40];
  __shared__ unsigned short Bh[128][40];
  __shared__ unsigned short Bl[128][40];
  const int tid = threadIdx.x;
  const int m0 = blockIdx.x * 128;
  const int n0 = blockIdx.y * 128;
  const int dir = (MODE == 3) ? blockIdx.z : 0;

  const int sr = tid >> 1;
  const int sh = tid & 1;
  const float* arow = nullptr;
  const unsigned short* ahrow = nullptr;
  const unsigned short* alrow = nullptr;
  if (MODE == 3) {
    int tl = m0 >> 8;
    int b = (m0 & 255) + sr;
    int t = c * CHUNK + tl;
    int len = lens[b];
    int r = (dir == 0) ? t : ((t < len) ? (len - 1 - t) : t);
    arow = A + ((size_t)b * TT + r) * DD;
  } else if (MODE == 0) {
    arow = A + (size_t)(m0 + sr) * K;
  } else {
    ahrow = Ahi + (size_t)(m0 + sr) * K;
    alrow = Alo + (size_t)(m0 + sr) * K;
  }
  const unsigned short* bhrow = Bhi + ((size_t)dir * N + n0 + sr) * K;
  const unsigned short* blrow = Blo + ((size_t)dir * N + n0 + sr) * K;

  const int wave = tid >> 6, lane = tid & 63;
  const int wm = wave & 1, wn = wave >> 1;
  const int quad = lane >> 4, l15 = lane & 15;

  f4v acc[4][4];
#pragma unroll
  for (int i = 0; i < 4; ++i)
#pragma unroll
    for (int j = 0; j < 4; ++j) acc[i][j] = (f4v){0.f, 0.f, 0.f, 0.f};

#pragma unroll 1
  for (int k0 = 0; k0 < K; k0 += 32) {
    __syncthreads();
    if (MODE == 1 || MODE == 2) {
      const uint4* ph = (const uint4*)(ahrow + k0 + sh * 16);
      uint4* dh = (uint4*)&Ah[sr][sh * 16];
      dh[0] = ph[0]; dh[1] = ph[1];
      const uint4* pl = (const uint4*)(alrow + k0 + sh * 16);
      uint4* dl = (uint4*)&Al[sr][sh * 16];
      dl[0] = pl[0]; dl[1] = pl[1];
    } else {
      const float4* pa = (const float4*)(arow + k0 + sh * 16);
      float4 v0 = pa[0], v1 = pa[1], v2 = pa[2], v3 = pa[3];
      unsigned h[8], l[8];
      cvt2(v0.x, v0.y, h[0], l[0]); cvt2(v0.z, v0.w, h[1], l[1]);
      cvt2(v1.x, v1.y, h[2], l[2]); cvt2(v1.z, v1.w, h[3], l[3]);
      cvt2(v2.x, v2.y, h[4], l[4]); cvt2(v2.z, v2.w, h[5], l[5]);
      cvt2(v3.x, v3.y, h[6], l[6]); cvt2(v3.z, v3.w, h[7], l[7]);
      uint4* dh = (uint4*)&Ah[sr][sh * 16];
      dh[0] = make_uint4(h[0], h[1], h[2], h[3]);
      dh[1] = make_uint4(h[4], h[5], h[6], h[7]);
      uint4* dl = (uint4*)&Al[sr][sh * 16];
      dl[0] = make_uint4(l[0], l[1], l[2], l[3]);
      dl[1] = make_uint4(l[4], l[5], l[6], l[7]);
    }
    {
      const uint4* pbh = (const uint4*)(bhrow + k0 + sh * 16);
      uint4* dbh = (uint4*)&Bh[sr][sh * 16];
      dbh[0] = pbh[0]; dbh[1] = pbh[1];
      const uint4* pbl = (const uint4*)(blrow + k0 + sh * 16);
      uint4* dbl = (uint4*)&Bl[sr][sh * 16];
      dbl[0] = pbl[0]; dbl[1] = pbl[1];
    }
    __syncthreads();
    s8v ah[4], al[4], bh[4], bl[4];
#pragma unroll
    for (int mi = 0; mi < 4; ++mi) {
      ah[mi] = *(const s8v*)&Ah[wm * 64 + mi * 16 + l15][quad * 8];
      al[mi] = *(const s8v*)&Al[wm * 64 + mi * 16 + l15][quad * 8];
    }
#pragma unroll
    for (int ni = 0; ni < 4; ++ni) {
      bh[ni] = *(const s8v*)&Bh[wn * 64 + ni * 16 + l15][quad * 8];
      bl[ni] = *(const s8v*)&Bl[wn * 64 + ni * 16 + l15][quad * 8];
    }
#pragma unroll
    for (int mi = 0; mi < 4; ++mi)
#pragma unroll
      for (int ni = 0; ni < 4; ++ni) {
        acc[mi][ni] = __builtin_amdgcn_mfma_f32_16x16x32_bf16(ah[mi], bh[ni], acc[mi][ni], 0, 0, 0);
        acc[mi][ni] = __builtin_amdgcn_mfma_f32_16x16x32_bf16(al[mi], bh[ni], acc[mi][ni], 0, 0, 0);
        acc[mi][ni] = __builtin_amdgcn_mfma_f32_16x16x32_bf16(ah[mi], bl[ni], acc[mi][ni], 0, 0, 0);
      }
  }

  // epilogue; C/D layout: col = l15, row = quad*4 + reg
  const int rb = wm * 64;
  if (MODE == 0 || MODE == 3) {
    float* Cb;
    const float* bp = bias;
    if (MODE == 3) {
      int tl = m0 >> 8;
      Cb = C + (((size_t)dir * CHUNK + tl) * 256 + (m0 & 255)) * (size_t)N;
      bp = bias + (size_t)dir * N;
    } else {
      Cb = C + (size_t)m0 * N;
    }
#pragma unroll
    for (int mi = 0; mi < 4; ++mi)
#pragma unroll
      for (int ni = 0; ni < 4; ++ni) {
        int col = n0 + wn * 64 + ni * 16 + l15;
        float bv = bp[col];
#pragma unroll
        for (int r = 0; r < 4; ++r) {
          int row = rb + mi * 16 + quad * 4 + r;
          Cb[(size_t)row * N + col] = acc[mi][ni][r] + bv;
        }
      }
  } else if (MODE == 1) {
#pragma unroll
    for (int ni = 0; ni < 4; ++ni) {
      int col = n0 + wn * 64 + ni * 16 + l15;
      float bv = bias[col];
      float s = 0.f, q = 0.f;
#pragma unroll
      for (int mi = 0; mi < 4; ++mi)
#pragma unroll
        for (int r = 0; r < 4; ++r) {
          float z = acc[mi][ni][r] + bv;
          s += z;
          q += z * z;
        }
      s += __shfl_xor(s, 16); s += __shfl_xor(s, 32);
      q += __shfl_xor(q, 16); q += __shfl_xor(q, 32);
      if (quad == 0) {
        atomicAdd(&cs[col], s);
        atomicAdd(&csq[col], q);
      }
    }
  } else {  // MODE 2
#pragma unroll
    for (int mi = 0; mi < 4; ++mi) {
      float rv[4] = {0.f, 0.f, 0.f, 0.f};
#pragma unroll
      for (int ni = 0; ni < 4; ++ni) {
        int col = n0 + wn * 64 + ni * 16 + l15;
        float bv = bias[col], mc = bnm[col], ic = bni[col], wc = s2w[col];
#pragma unroll
        for (int r = 0; r < 4; ++r) {
          float z = acc[mi][ni][r] + bv;
          rv[r] += leakyf((z - mc) * ic) * wc;
        }
      }
#pragma unroll
      for (int r = 0; r < 4; ++r) {
        float v = rv[r];
        v += __shfl_xor(v, 1); v += __shfl_xor(v, 2);
        v += __shfl_xor(v, 4); v += __shfl_xor(v, 8);
        if (l15 == 0) atomicAdd(&alpha[m0 + rb + mi * 16 + quad * 4 + r], v);
      }
    }
  }
}

// ---------------- per-step LSTM recurrence kernel (one launch per t) ----------------
// grid (4 b-tiles x 64, 32 j-tiles x 16, 2 dirs) = 256 blocks; 128 KB LDS -> 1 block/CU.
// Whh tile (4 gates x 16 j) x K=512 hi+lo staged ONCE per launch into XOR-swizzled LDS
// (slot' = slot ^ (row&7) -> conflict-free ds_read_b128); single __syncthreads.
// h state packed bf16 hi/lo octet-interleaved in global ([b][64 oct][8 hi + 8 lo]);
// A-fragments = one contiguous 32B read per lane per k-octet, global -> VGPR direct.
// A/XG/Cst prefetched before the barrier so global latency overlaps B staging.
// Step ordering = kernel launch boundary (cheapest agent-wide sync; round-1 showed
// spin+threadfence costs ~8-10us/step vs ~3us launch).
__global__ __launch_bounds__(256, 1) void k_step(
    const unsigned short* __restrict__ Bhi, const unsigned short* __restrict__ Blo,
    const float* __restrict__ XG, const int* __restrict__ lens,
    unsigned short* __restrict__ Hpk,   // [2par][2dir][BB][64oct][16]
    float* __restrict__ Cst,
    unsigned short* __restrict__ Hhi, unsigned short* __restrict__ Hlo,
    int t) {
  __shared__ unsigned short Bsh[64 * 512];   // 64 KB
  __shared__ unsigned short Bsl[64 * 512];   // 64 KB
  const int tid = threadIdx.x;
  const int b0 = blockIdx.x * 64;
  const int j0 = blockIdx.y * 16;
  const int dir = blockIdx.z;
  const int tl = t & (CHUNK - 1);
  const int rpar = t & 1, wpar = (t + 1) & 1;

  const int wave = tid >> 6, lane = tid & 63;
  const int quad = lane >> 4, l15 = lane & 15;
  const int j = j0 + l15;
  const int amrow = b0 + wave * 16 + l15;    // A-frag row this lane reads

  // ---- A-fragment prefetch (packed h state: per octet 8 hi + 8 lo u16 = 32B) ----
  const unsigned short* Ab = Hpk + (((size_t)rpar * 2 + dir) * BB + amrow) * 1024;
  uint4 ahv[16], alv[16];
#pragma unroll
  for (int ks = 0; ks < 16; ++ks) {
    const uint4* p = (const uint4*)Ab + (size_t)(ks * 4 + quad) * 2;
    ahv[ks] = p[0];
    alv[ks] = p[1];
  }

  // ---- epilogue-input prefetch ----
  int bv[4], lenv[4];
  float cstate[4], xgv[4][4];
  size_t sidx[4];
#pragma unroll
  for (int r = 0; r < 4; ++r) {
    bv[r] = b0 + wave * 16 + quad * 4 + r;
    lenv[r] = lens[bv[r]];
    sidx[r] = ((size_t)dir * BB + bv[r]) * HH + j;
    cstate[r] = Cst[sidx[r]];
    size_t xgb = (((size_t)dir * CHUNK + tl) * BB + bv[r]) * (size_t)G4 + j;
#pragma unroll
    for (int g = 0; g < 4; ++g) xgv[r][g] = XG[xgb + (size_t)g * HH];
  }

  // ---- stage Whh tile into LDS with 16B-slot XOR swizzle (once per launch) ----
#pragma unroll
  for (int ii = 0; ii < 16; ++ii) {
    int i = ii * 256 + tid;                  // 64 rows x 64 uint4-slots
    int row = i >> 6, s = i & 63;
    int sp = s ^ (row & 7);
    int grow = dir * G4 + (row >> 4) * HH + j0 + (row & 15);  // gate*512 + j
    ((uint4*)Bsh)[row * 64 + sp] = ((const uint4*)(Bhi + (size_t)grow * HH))[s];
    ((uint4*)Bsl)[row * 64 + sp] = ((const uint4*)(Blo + (size_t)grow * HH))[s];
  }
  __syncthreads();

  // ---- K-loop: pure ds_read + MFMA ----
  f4v acc[4];
#pragma unroll
  for (int g = 0; g < 4; ++g) acc[g] = (f4v){0.f, 0.f, 0.f, 0.f};
#pragma unroll
  for (int ks = 0; ks < 16; ++ks) {
    s8v ah = *(s8v*)&ahv[ks];
    s8v al = *(s8v*)&alv[ks];
#pragma unroll
    for (int g = 0; g < 4; ++g) {
      int row = g * 16 + l15;
      int sp = (ks * 4 + quad) ^ (l15 & 7);  // row&7 == l15&7
      s8v bh = *(const s8v*)(Bsh + row * 512 + sp * 8);
      s8v bl = *(const s8v*)(Bsl + row * 512 + sp * 8);
      acc[g] = __builtin_amdgcn_mfma_f32_16x16x32_bf16(ah, bh, acc[g], 0, 0, 0);
      acc[g] = __builtin_amdgcn_mfma_f32_16x16x32_bf16(al, bh, acc[g], 0, 0, 0);
      acc[g] = __builtin_amdgcn_mfma_f32_16x16x32_bf16(ah, bl, acc[g], 0, 0, 0);
    }
  }

  // ---- epilogue: fused cell update; packed-split h to write-parity buffer ----
  unsigned short* Wb = Hpk + (((size_t)wpar * 2 + dir) * BB) * 1024;
  const unsigned short* Rb = Hpk + (((size_t)rpar * 2 + dir) * BB) * 1024;
  const int oj = (j >> 3) * 16 + (j & 7);
#pragma unroll
  for (int r = 0; r < 4; ++r) {
    if (t < lenv[r]) {
      float gi = acc[0][r] + xgv[r][0];
      float gf = acc[1][r] + xgv[r][1];
      float gg = acc[2][r] + xgv[r][2];
      float go = acc[3][r] + xgv[r][3];
      float cn = sigmf(gf) * cstate[r] + sigmf(gi) * tanhfast(gg);
      float hn = sigmf(go) * tanhfast(cn);
      Cst[sidx[r]] = cn;
      unsigned hb = __float_as_uint(hn);
      unsigned short h16 = (unsigned short)(hb >> 16);
      unsigned short l16 =
          (unsigned short)(__float_as_uint(hn - __uint_as_float(hb & 0xffff0000u)) >> 16);
      size_t wi = (size_t)bv[r] * 1024 + oj;
      Wb[wi] = h16;
      Wb[wi + 8] = l16;
      int ro = dir ? (lenv[r] - 1 - t) : t;
      size_t hidx = ((size_t)bv[r] * TT + ro) * DD + (size_t)dir * HH + j;
      Hhi[hidx] = h16;
      Hlo[hidx] = l16;
    } else {  // frozen row: copy through to write-parity buffer (only t >= 64)
      size_t wi = (size_t)bv[r] * 1024 + oj;
      Wb[wi] = Rb[wi];
      Wb[wi + 8] = Rb[wi + 8];
    }
  }
}

__global__ __launch_bounds__(256) void k_bnfinal(const float* __restrict__ cs, const float* __restrict__ csq,
                                                 float* __restrict__ bnm, float* __restrict__ bni, float invN) {
  int i = blockIdx.x * 256 + threadIdx.x;
  if (i < DD) {
    float m = cs[i] * invN;
    float v = csq[i] * invN - m * m;
    bnm[i] = m;
    bni[i] = rsqrtf(v + 1e-5f);
  }
}

__global__ __launch_bounds__(128) void k_asum(float* __restrict__ alpha, const int* __restrict__ lens) {
  int b = blockIdx.x;
  int t = threadIdx.x;
  int len = lens[b];
  float v = (t < len) ? alpha[b * TT + t] : 0.f;
  float s = v;
  for (int o = 32; o > 0; o >>= 1) s += __shfl_down(s, o);
  __shared__ float sw[2];
  if ((t & 63) == 0) sw[t >> 6] = s;
  __syncthreads();
  float S = sw[0] + sw[1] + 1e-9f;
  alpha[b * TT + t] = v / S;
}

__global__ __launch_bounds__(256) void k_U(const unsigned short* __restrict__ Hhi,
                                           const unsigned short* __restrict__ Hlo,
                                           const float* __restrict__ alpha,
                                           float* __restrict__ U) {
  int b = blockIdx.x;
  int tid = threadIdx.x;
  __shared__ float al[TT];
  if (tid < TT) al[tid] = alpha[b * TT + tid];
  __syncthreads();
  float4 s = make_float4(0.f, 0.f, 0.f, 0.f);
  size_t base = (size_t)b * TT * DD + tid * 4;
#pragma unroll 4
  for (int t = 0; t < TT; ++t) {
    float a = al[t];
    ushort4 hv = *(const ushort4*)(Hhi + base + (size_t)t * DD);
    ushort4 lv = *(const ushort4*)(Hlo + base + (size_t)t * DD);
    s.x += a * (__uint_as_float((unsigned)hv.x << 16) + __uint_as_float((unsigned)lv.x << 16));
    s.y += a * (__uint_as_float((unsigned)hv.y << 16) + __uint_as_float((unsigned)lv.y << 16));
    s.z += a * (__uint_as_float((unsigned)hv.z << 16) + __uint_as_float((unsigned)lv.z << 16));
    s.w += a * (__uint_as_float((unsigned)hv.w << 16) + __uint_as_float((unsigned)lv.w << 16));
  }
  *(float4*)(U + (size_t)b * DD + tid * 4) = s;
}

__global__ __launch_bounds__(256) void k_p2a(const float* __restrict__ U,
                                             const int* __restrict__ emoI,
                                             const int* __restrict__ cauI,
                                             float* __restrict__ chunkEmb) {
  int e = blockIdx.x;
  int tid = threadIdx.x;
  __shared__ float emoS[DD];
  __shared__ float sc[NCK][16];
  const float* Ue = U + (size_t)emoI[e] * DD;
  for (int i = tid; i < DD; i += 256) emoS[i] = Ue[i];
  __syncthreads();
  int w = tid >> 6, lane = tid & 63;
  for (int p = w; p < 128; p += 4) {
    const float* y = U + (size_t)cauI[p] * DD;
    float s = 0;
    for (int d = lane; d < DD; d += 64) s += emoS[d] * y[d];
    for (int o = 32; o > 0; o >>= 1) s += __shfl_down(s, o);
    if (lane == 0) sc[p >> 4][p & 15] = s;
  }
  __syncthreads();
  if (tid < NCK) {
    float mx = -1e30f;
    for (int c = 0; c < 16; ++c) mx = fmaxf(mx, sc[tid][c]);
    float sum = 0;
    for (int c = 0; c < 16; ++c) {
      float ev = __expf(sc[tid][c] - mx);
      sc[tid][c] = ev;
      sum += ev;
    }
    float inv = 1.f / sum;
    for (int c = 0; c < 16; ++c) sc[tid][c] *= inv;
  }
  __syncthreads();
  int d = tid * 4;
  for (int nn = 0; nn < NCK; ++nn) {
    float4 s = make_float4(0.f, 0.f, 0.f, 0.f);
    for (int c = 0; c < 16; ++c) {
      float wc = sc[nn][c];
      float4 y = *(const float4*)(U + (size_t)cauI[nn * 16 + c] * DD + d);
      s.x += wc * y.x; s.y += wc * y.y; s.z += wc * y.z; s.w += wc * y.w;
    }
    *(float4*)(chunkEmb + ((size_t)e * NCK + nn) * DD + d) = s;
  }
}

__global__ __launch_bounds__(256) void k_delta2(const float* __restrict__ U,
                                                const int* __restrict__ emoI,
                                                const float* __restrict__ chunkEmb,
                                                const float* __restrict__ pos,
                                                float* __restrict__ delta2) {
  int e = blockIdx.x >> 3, nn = blockIdx.x & 7;
  int tid = threadIdx.x;
  const float* emo = U + (size_t)emoI[e] * DD;
  const float* y = chunkEmb + ((size_t)e * NCK + nn) * DD;
  __shared__ float s4[4];
  float ds = 0;
  for (int d = tid; d < DD; d += 256) {
    float df = emo[d] - y[d];
    ds += df * df;
  }
  float dist = sqrtf(blk_sum(ds, s4));
  float* out = delta2 + ((size_t)e * NCK + nn) * K3PAD;
  for (int c = tid; c < K3PAD; c += 256) {
    float v;
    if (c < 1024) v = emo[c];
    else if (c < 2048) v = y[c - 1024];
    else if (c == 2048) v = dist;
    else if (c < 3073) { int d = c - 2049; v = emo[d] * y[d]; }
    else if (c < 3123) v = pos[((size_t)e * NCK + nn) * PPP + (c - 3073)];
    else v = 0.f;
    out[c] = v;
  }
}

__global__ __launch_bounds__(256) void k_bnstats(const float* __restrict__ X,
                                                 float* __restrict__ bm, float* __restrict__ bi, int R) {
  int gid = blockIdx.x * 256 + threadIdx.x;  // NE*DD
  int e = gid >> 10, col = gid & 1023;
  const float* p = X + (size_t)e * R * DD + col;
  float s = 0, s2 = 0;
  for (int r = 0; r < R; ++r) {
    float v = p[(size_t)r * DD];
    s += v;
    s2 += v * v;
  }
  float m = s / R;
  float var = s2 / R - m * m;
  bm[gid] = m;
  bi[gid] = rsqrtf(var + 1e-5f);
}

__global__ __launch_bounds__(256) void k_out2(const float* __restrict__ h2,
                                              const float* __restrict__ bm, const float* __restrict__ bi,
                                              const float* __restrict__ Wo, const float* __restrict__ Wob,
                                              float* __restrict__ out, float* __restrict__ extraf) {
  int e = blockIdx.x >> 3, nn = blockIdx.x & 7;
  int tid = threadIdx.x;
  const float* row = h2 + ((size_t)e * NCK + nn) * DD;
  float l0 = 0, l1 = 0;
  for (int col = tid; col < DD; col += 256) {
    float h = leakyf((row[col] - bm[e * DD + col]) * bi[e * DD + col]);
    l0 += h * Wo[col];
    l1 += h * Wo[DD + col];
  }
  __shared__ float s4[4];
  l0 = blk_sum(l0, s4);
  l1 = blk_sum(l1, s4);
  if (tid == 0) {
    l0 += Wob[0];
    l1 += Wob[1];
    float mx = fmaxf(l0, l1);
    float lse = mx + logf(__expf(l0 - mx) + __expf(l1 - mx));
    out[((size_t)e * NCK + nn) * 2 + 0] = l0 - lse;
    out[((size_t)e * NCK + nn) * 2 + 1] = l1 - lse;
    extraf[e * NCK + nn] = (l1 > l0) ? 1.f : 0.f;
  }
}

__global__ __launch_bounds__(256) void k_delta3(const float* __restrict__ U,
                                                const int* __restrict__ emoI,
                                                const int* __restrict__ cauI,
                                                const float* __restrict__ dis,
                                                const float* __restrict__ extraf,
                                                float* __restrict__ delta3) {
  int e = blockIdx.x >> 7, c = blockIdx.x & 127;
  int tid = threadIdx.x;
  const float* emo = U + (size_t)emoI[e] * DD;
  const float* y = U + (size_t)cauI[c] * DD;
  __shared__ float s4[4];
  float ds = 0;
  for (int d = tid; d < DD; d += 256) {
    float df = emo[d] - y[d];
    ds += df * df;
  }
  float dist = sqrtf(blk_sum(ds, s4));
  float ex = extraf[e * NCK + (c >> 4)];
  float* out = delta3 + ((size_t)e * NCC + c) * K3PAD;
  for (int col = tid; col < K3PAD; col += 256) {
    float v;
    if (col < 1024) v = emo[col];
    else if (col < 2048) v = y[col - 1024];
    else if (col == 2048) v = dist;
    else if (col < 3073) { int d = col - 2049; v = emo[d] * y[d]; }
    else if (col < 3123) v = dis[((size_t)e * NCC + c) * PPP + (col - 3073)];
    else if (col < 3173) v = ex;
    else v = 0.f;
    out[col] = v;
  }
}

__global__ __launch_bounds__(256) void k_p3(const float* __restrict__ h3,
                                            const float* __restrict__ bm, const float* __restrict__ bi,
                                            const float* __restrict__ cw, const float* __restrict__ cb,
                                            float* __restrict__ out) {
  int e = blockIdx.x >> 7, c = blockIdx.x & 127;
  int tid = threadIdx.x;
  const float* row = h3 + ((size_t)e * NCC + c) * DD;
  float l0 = 0, l1 = 0;
  for (int col = tid; col < DD; col += 256) {
    float h = leakyf((row[col] - bm[e * DD + col]) * bi[e * DD + col]);
    l0 += h * cw[col];
    l1 += h * cw[DD + col];
  }
  __shared__ float s4[4];
  l0 = blk_sum(l0, s4);
  l1 = blk_sum(l1, s4);
  if (tid == 0) {
    l0 += cb[0];
    l1 += cb[1];
    float mx = fmaxf(l0, l1);
    float lse = mx + logf(__expf(l0 - mx) + __expf(l1 - mx));
    out[((size_t)e * NCC + c) * 2 + 0] = l0 - lse;
    out[((size_t)e * NCC + c) * 2 + 1] = l1 - lse;
  }
}

__global__ __launch_bounds__(256) void k_L(const int* __restrict__ lab, float* __restrict__ out) {
  int i = blockIdx.x * 256 + threadIdx.x;  // 8192
  int e = i >> 7, c = i & 127;
  int a = lab[e * 3 + 0], b = lab[e * 3 + 1], d = lab[e * 3 + 2];
  out[i] = (a == c || b == c || d == c) ? 1.f : 0.f;
}

extern "C" void kernel_launch(void* const* d_in, const int* in_sizes, int n_in,
                              void* d_out, int out_size, void* d_ws, size_t ws_size,
                              hipStream_t stream) {
  (void)in_sizes; (void)n_in; (void)out_size; (void)ws_size;
  const float* X     = (const float*)d_in[0];
  const float* pos   = (const float*)d_in[1];
  const float* dis   = (const float*)d_in[2];
  const int*   lens  = (const int*)d_in[3];
  const int*   lab3  = (const int*)d_in[4];
  const int*   emoI  = (const int*)d_in[5];
  const int*   cauI  = (const int*)d_in[6];
  const float* Wih_f = (const float*)d_in[7];
  const float* Whh_f = (const float*)d_in[8];
  const float* bih_f = (const float*)d_in[9];
  const float* bhh_f = (const float*)d_in[10];
  const float* Wih_b = (const float*)d_in[11];
  const float* Whh_b = (const float*)d_in[12];
  const float* bih_b = (const float*)d_in[13];
  const float* bhh_b = (const float*)d_in[14];
  const float* s1w   = (const float*)d_in[15];
  const float* s1b   = (const float*)d_in[16];
  const float* s2w   = (const float*)d_in[17];
  const float* W2w   = (const float*)d_in[18];
  const float* W2b   = (const float*)d_in[19];
  const float* Wow   = (const float*)d_in[20];
  const float* Wob   = (const float*)d_in[21];
  const float* W3w   = (const float*)d_in[22];
  const float* W3b   = (const float*)d_in[23];
  const float* clsw  = (const float*)d_in[24];
  const float* clsb  = (const float*)d_in[25];
  float* ws = (float*)d_ws;
  float* out = (float*)d_out;

  unsigned short* Hhi = (unsigned short*)(ws + F_HSEQ);
  unsigned short* Hlo = Hhi + (size_t)NROWS * DD;
  unsigned short* WIHhi = (unsigned short*)(ws + F_WIH);
  unsigned short* WIHlo = WIHhi + (size_t)2 * 2048 * 1024;
  unsigned short* WHHhi = (unsigned short*)(ws + F_WHH);
  unsigned short* WHHlo = WHHhi + (size_t)2 * 2048 * 512;
  unsigned short* S1hi  = (unsigned short*)(ws + F_S1);
  unsigned short* S1lo  = S1hi + (size_t)1024 * 1024;
  unsigned short* W2hi  = (unsigned short*)(ws + F_W2);
  unsigned short* W2lo  = W2hi + (size_t)1024 * K3PAD;
  unsigned short* W3hi  = (unsigned short*)(ws + F_W3);
  unsigned short* W3lo  = W3hi + (size_t)1024 * K3PAD;
  unsigned short* Hpk   = (unsigned short*)(ws + F_HST);   // [2par][2dir][256][64oct][16]

  // zero-init read-before-write buffers (padded Hseq rows MUST be 0 for BN stats;
  // Hpk parity-0 must be 0 for t=0; Cst must be 0)
  hipMemsetAsync(ws + F_HSEQ, 0, (size_t)33554432 * sizeof(float), stream);  // Hhi+Hlo
  hipMemsetAsync(ws + F_HST, 0, (size_t)(524288 + 262144) * sizeof(float), stream);  // Hpk + CST
  hipMemsetAsync(ws + F_CS, 0, (size_t)2048 * sizeof(float), stream);                // CS + CSQ
  hipMemsetAsync(ws + F_ALPHA, 0, (size_t)32768 * sizeof(float), stream);

  // weight converts (fp32 -> bf16 hi/lo, n-major = native torch layout)
  k_cvt<<<2048, 256, 0, stream>>>(Wih_f, WIHhi, WIHlo, 1024, 1024);
  k_cvt<<<2048, 256, 0, stream>>>(Wih_b, WIHhi + (size_t)2048 * 1024, WIHlo + (size_t)2048 * 1024, 1024, 1024);
  k_cvt<<<2048, 256, 0, stream>>>(Whh_f, WHHhi, WHHlo, 512, 512);
  k_cvt<<<2048, 256, 0, stream>>>(Whh_b, WHHhi + (size_t)2048 * 512, WHHlo + (size_t)2048 * 512, 512, 512);
  k_cvt<<<1024, 256, 0, stream>>>(s1w, S1hi, S1lo, 1024, 1024);
  k_cvt<<<1024, 256, 0, stream>>>(W2w, W2hi, W2lo, 3123, K3PAD);
  k_cvt<<<1024, 256, 0, stream>>>(W3w, W3hi, W3lo, 3173, K3PAD);
  k_biasc<<<16, 256, 0, stream>>>(bih_f, bhh_f, bih_b, bhh_b, ws + F_BIASC);

  // BiLSTM: chunked input-projection MFMA GEMMs + per-step fused recurrence
  for (int c = 0; c < TT / CHUNK; ++c) {
    k_mf<3><<<dim3(16, 16, 2), 256, 0, stream>>>(X, nullptr, nullptr, WIHhi, WIHlo,
                                                 ws + F_BIASC, ws + F_XG,
                                                 2048, 2048, 1024, lens, c,
                                                 nullptr, nullptr, nullptr, nullptr, nullptr, nullptr);
    for (int tt = 0; tt < CHUNK; ++tt) {
      int t = c * CHUNK + tt;
      k_step<<<dim3(4, 32, 2), 256, 0, stream>>>(WHHhi, WHHlo, ws + F_XG, lens,
                                                 Hpk, ws + F_CST, Hhi, Hlo, t);
    }
  }

  // attention: two-pass z (BN stats, then masked-linear attention weights); A pre-split
  k_mf<1><<<dim3(256, 8), 256, 0, stream>>>(nullptr, Hhi, Hlo, S1hi, S1lo, s1b, nullptr,
                                            NROWS, 1024, 1024, nullptr, 0,
                                            nullptr, nullptr, nullptr,
                                            ws + F_CS, ws + F_CSQ, nullptr);
  k_bnfinal<<<4, 256, 0, stream>>>(ws + F_CS, ws + F_CSQ, ws + F_BNM, ws + F_BNI, 1.f / NROWS);
  k_mf<2><<<dim3(256, 8), 256, 0, stream>>>(nullptr, Hhi, Hlo, S1hi, S1lo, s1b, nullptr,
                                            NROWS, 1024, 1024, nullptr, 0,
                                            ws + F_BNM, ws + F_BNI, s2w,
                                            nullptr, nullptr, ws + F_ALPHA);
  k_asum<<<BB, TT, 0, stream>>>(ws + F_ALPHA, lens);
  k_U<<<BB, 256, 0, stream>>>(Hhi, Hlo, ws + F_ALPHA, ws + F_U);

  // phase 2 (D2/CHE overlay dead Hseq region)
  k_p2a<<<NE, 256, 0, stream>>>(ws + F_U, emoI, cauI, ws + F_CHE);
  k_delta2<<<NE * NCK, 256, 0, stream>>>(ws + F_U, emoI, ws + F_CHE, pos, ws + F_D2);
  k_mf<0><<<dim3(4, 8), 256, 0, stream>>>(ws + F_D2, nullptr, nullptr, W2hi, W2lo, W2b, ws + F_H2,
                                          512, 1024, K3PAD, nullptr, 0,
                                          nullptr, nullptr, nullptr, nullptr, nullptr, nullptr);
  k_bnstats<<<256, 256, 0, stream>>>(ws + F_H2, ws + F_BN2M, ws + F_BN2I, NCK);
  k_out2<<<NE * NCK, 256, 0, stream>>>(ws + F_H2, ws + F_BN2M, ws + F_BN2I, Wow, Wob,
                                       out, ws + F_EXTRA);

  // phase 3 (D3 overlays Hseq; H3 overlays dead XG)
  k_delta3<<<NE * NCC, 256, 0, stream>>>(ws + F_U, emoI, cauI, dis, ws + F_EXTRA, ws + F_D3);
  k_mf<0><<<dim3(64, 8), 256, 0, stream>>>(ws + F_D3, nullptr, nullptr, W3hi, W3lo, W3b, ws + F_H3,
                                           8192, 1024, K3PAD, nullptr, 0,
                                           nullptr, nullptr, nullptr, nullptr, nullptr, nullptr);
  k_bnstats<<<256, 256, 0, stream>>>(ws + F_H3, ws + F_BN3M, ws + F_BN3I, NCC);
  k_p3<<<NE * NCC, 256, 0, stream>>>(ws + F_H3, ws + F_BN3M, ws + F_BN3I, clsw, clsb, out + 1024);
  k_L<<<32, 256, 0, stream>>>(lab3, out + 17408);
}

// Round 3
// 4028.350 us; speedup vs baseline: 1.3266x; 1.0582x over previous
//
#include <hip/hip_runtime.h>
#include <math.h>

// ---------------- problem dims ----------------
#define DD    1024
#define TT    128
#define BB    256
#define NE    64
#define NCC   128
#define PPP   50
#define NCK   8
#define HH    512
#define G4    2048     // 4*HH
#define NROWS 32768    // BB*TT
#define K3PAD 3200     // padded K for phase2/3 GEMMs (3123 / 3173 -> 3200)
#define CHUNK 8        // timesteps per XG chunk

// ---------------- workspace layout (float offsets) ----------------
#define F_HSEQ  0ull            // Hseq hi [32768][1024] u16 + lo (33,554,432 float-slots); later D2/CHE/D3
#define F_XG    33554432ull     // [2][CHUNK][256][2048] fp32 8,388,608 ; later H3
#define F_WIH   41943040ull     // bf16 hi[2][2048][1024] + lo  (4,194,304 float-slots)
#define F_WHH   46137344ull     // bf16 hi[2][2048][512] + lo   (2,097,152)
#define F_S1    48234496ull     // bf16 hi[1024][1024] + lo     (1,048,576)
#define F_W2    49283072ull     // bf16 hi[1024][3200] + lo     (3,276,800)
#define F_W3    52559872ull     // bf16 hi[1024][3200] + lo     (3,276,800)
#define F_BIASC 56885248ull     // [2][2048]
#define F_HST   56889344ull     // packed h state [2par][2dir][256][64oct][16] u16 = 524,288 float-slots
#define F_CST   57413632ull     // [2][256][512] = 262,144
#define F_CS    57675776ull
#define F_CSQ   57676800ull
#define F_BNM   57677824ull
#define F_BNI   57678848ull
#define F_ALPHA 57679872ull     // [BB*TT]
#define F_U     57712640ull     // [BB,DD] 262,144
#define F_H2    57974784ull     // [64,8,1024] 524,288
#define F_BN2M  58499072ull
#define F_BN2I  58564608ull
#define F_EXTRA 58630144ull
#define F_BN3M  58631168ull
#define F_BN3I  58696704ull

#define F_D2    F_HSEQ
#define F_CHE   (F_HSEQ + 26214400ull)
#define F_D3    F_HSEQ
#define F_H3    F_XG

typedef short s8v __attribute__((ext_vector_type(8)));
typedef float f4v __attribute__((ext_vector_type(4)));

__device__ __forceinline__ float leakyf(float x) { return x >= 0.f ? x : 0.01f * x; }
__device__ __forceinline__ float sigmf(float x)  { return 1.f / (1.f + __expf(-x)); }
__device__ __forceinline__ float tanhfast(float x) {
  float e = __expf(2.f * x);          // +inf for large x -> 1; 0 for very negative -> -1
  return 1.f - 2.f / (e + 1.f);
}

__device__ __forceinline__ float blk_sum(float v, float* s4) {
  for (int o = 32; o > 0; o >>= 1) v += __shfl_down(v, o);
  __syncthreads();
  if ((threadIdx.x & 63) == 0) s4[threadIdx.x >> 6] = v;
  __syncthreads();
  return s4[0] + s4[1] + s4[2] + s4[3];
}

// pack 2 fp32 -> (hi bf16 pair, lo bf16 pair); hi = truncation, lo = exact residual truncated
__device__ __forceinline__ void cvt2(float x0, float x1, unsigned& hi, unsigned& lo) {
  unsigned b0 = __float_as_uint(x0), b1 = __float_as_uint(x1);
  hi = (b0 >> 16) | (b1 & 0xffff0000u);
  float h0 = __uint_as_float(b0 & 0xffff0000u);
  float h1 = __uint_as_float(b1 & 0xffff0000u);
  unsigned l0 = __float_as_uint(x0 - h0);
  unsigned l1 = __float_as_uint(x1 - h1);
  lo = (l0 >> 16) | (l1 & 0xffff0000u);
}

// weight convert: src fp32 [N][Ks] row-major -> hi/lo bf16 [N][Kd] (zero-padded)
__global__ __launch_bounds__(256) void k_cvt(const float* __restrict__ src,
                                             unsigned short* __restrict__ hi,
                                             unsigned short* __restrict__ lo,
                                             int Ks, int Kd) {
  int n = blockIdx.x;
  for (int k = threadIdx.x; k < Kd; k += 256) {
    float v = (k < Ks) ? src[(size_t)n * Ks + k] : 0.f;
    unsigned b = __float_as_uint(v);
    float h = __uint_as_float(b & 0xffff0000u);
    hi[(size_t)n * Kd + k] = (unsigned short)(b >> 16);
    lo[(size_t)n * Kd + k] = (unsigned short)(__float_as_uint(v - h) >> 16);
  }
}

__global__ __launch_bounds__(256) void k_biasc(const float* __restrict__ bf1, const float* __restrict__ bf2,
                                               const float* __restrict__ bb1, const float* __restrict__ bb2,
                                               float* __restrict__ out) {
  int i = blockIdx.x * 256 + threadIdx.x;  // 4096
  if (i < G4) out[i] = bf1[i] + bf2[i];
  else        out[i] = bb1[i - G4] + bb2[i - G4];
}

// ---------------- MFMA GEMM, 128x128 tile, split-bf16 3-term (fp32-accurate) ----------------
// B bf16 hi/lo n-major [N][K].
// MODE 0 STORE: A fp32; C = A@B + bias                         (p2/p3 GEMMs)
// MODE 1 STATS: A pre-split hi/lo; atomic col sum/sumsq        (z pass 1)
// MODE 2 ALPHA: A pre-split hi/lo; atomic row sum of leaky((z-bnm)*bni)*s2w  (z pass 2)
// MODE 3 XG:    A fp32 rows gathered from X via lens; dir = blockIdx.z
template <int MODE>
__global__ __launch_bounds__(256, 2) void k_mf(
    const float* __restrict__ A,
    const unsigned short* __restrict__ Ahi, const unsigned short* __restrict__ Alo,
    const unsigned short* __restrict__ Bhi, const unsigned short* __restrict__ Blo,
    const float* __restrict__ bias, float* __restrict__ C, int M, int N, int K,
    const int* __restrict__ lens, int c,
    const float* __restrict__ bnm, const float* __restrict__ bni,
    const float* __restrict__ s2w, float* __restrict__ cs,
    float* __restrict__ csq, float* __restrict__ alpha) {
  __shared__ unsigned short Ah[128][40];
  __shared__ unsigned short Al[128][40];
  __shared__ unsigned short Bh[128][40];
  __shared__ unsigned short Bl[128][40];
  const int tid = threadIdx.x;
  const int m0 = blockIdx.x * 128;
  const int n0 = blockIdx.y * 128;
  const int dir = (MODE == 3) ? blockIdx.z : 0;

  const int sr = tid >> 1;
  const int sh = tid & 1;
  const float* arow = nullptr;
  const unsigned short* ahrow = nullptr;
  const unsigned short* alrow = nullptr;
  if (MODE == 3) {
    int tl = m0 >> 8;
    int b = (m0 & 255) + sr;
    int t = c * CHUNK + tl;
    int len = lens[b];
    int r = (dir == 0) ? t : ((t < len) ? (len - 1 - t) : t);
    arow = A + ((size_t)b * TT + r) * DD;
  } else if (MODE == 0) {
    arow = A + (size_t)(m0 + sr) * K;
  } else {
    ahrow = Ahi + (size_t)(m0 + sr) * K;
    alrow = Alo + (size_t)(m0 + sr) * K;
  }
  const unsigned short* bhrow = Bhi + ((size_t)dir * N + n0 + sr) * K;
  const unsigned short* blrow = Blo + ((size_t)dir * N + n0 + sr) * K;

  const int wave = tid >> 6, lane = tid & 63;
  const int wm = wave & 1, wn = wave >> 1;
  const int quad = lane >> 4, l15 = lane & 15;

  f4v acc[4][4];
#pragma unroll
  for (int i = 0; i < 4; ++i)
#pragma unroll
    for (int j = 0; j < 4; ++j) acc[i][j] = (f4v){0.f, 0.f, 0.f, 0.f};

#pragma unroll 1
  for (int k0 = 0; k0 < K; k0 += 32) {
    __syncthreads();
    if (MODE == 1 || MODE == 2) {
      const uint4* ph = (const uint4*)(ahrow + k0 + sh * 16);
      uint4* dh = (uint4*)&Ah[sr][sh * 16];
      dh[0] = ph[0]; dh[1] = ph[1];
      const uint4* pl = (const uint4*)(alrow + k0 + sh * 16);
      uint4* dl = (uint4*)&Al[sr][sh * 16];
      dl[0] = pl[0]; dl[1] = pl[1];
    } else {
      const float4* pa = (const float4*)(arow + k0 + sh * 16);
      float4 v0 = pa[0], v1 = pa[1], v2 = pa[2], v3 = pa[3];
      unsigned h[8], l[8];
      cvt2(v0.x, v0.y, h[0], l[0]); cvt2(v0.z, v0.w, h[1], l[1]);
      cvt2(v1.x, v1.y, h[2], l[2]); cvt2(v1.z, v1.w, h[3], l[3]);
      cvt2(v2.x, v2.y, h[4], l[4]); cvt2(v2.z, v2.w, h[5], l[5]);
      cvt2(v3.x, v3.y, h[6], l[6]); cvt2(v3.z, v3.w, h[7], l[7]);
      uint4* dh = (uint4*)&Ah[sr][sh * 16];
      dh[0] = make_uint4(h[0], h[1], h[2], h[3]);
      dh[1] = make_uint4(h[4], h[5], h[6], h[7]);
      uint4* dl = (uint4*)&Al[sr][sh * 16];
      dl[0] = make_uint4(l[0], l[1], l[2], l[3]);
      dl[1] = make_uint4(l[4], l[5], l[6], l[7]);
    }
    {
      const uint4* pbh = (const uint4*)(bhrow + k0 + sh * 16);
      uint4* dbh = (uint4*)&Bh[sr][sh * 16];
      dbh[0] = pbh[0]; dbh[1] = pbh[1];
      const uint4* pbl = (const uint4*)(blrow + k0 + sh * 16);
      uint4* dbl = (uint4*)&Bl[sr][sh * 16];
      dbl[0] = pbl[0]; dbl[1] = pbl[1];
    }
    __syncthreads();
    s8v ah[4], al[4], bh[4], bl[4];
#pragma unroll
    for (int mi = 0; mi < 4; ++mi) {
      ah[mi] = *(const s8v*)&Ah[wm * 64 + mi * 16 + l15][quad * 8];
      al[mi] = *(const s8v*)&Al[wm * 64 + mi * 16 + l15][quad * 8];
    }
#pragma unroll
    for (int ni = 0; ni < 4; ++ni) {
      bh[ni] = *(const s8v*)&Bh[wn * 64 + ni * 16 + l15][quad * 8];
      bl[ni] = *(const s8v*)&Bl[wn * 64 + ni * 16 + l15][quad * 8];
    }
#pragma unroll
    for (int mi = 0; mi < 4; ++mi)
#pragma unroll
      for (int ni = 0; ni < 4; ++ni) {
        acc[mi][ni] = __builtin_amdgcn_mfma_f32_16x16x32_bf16(ah[mi], bh[ni], acc[mi][ni], 0, 0, 0);
        acc[mi][ni] = __builtin_amdgcn_mfma_f32_16x16x32_bf16(al[mi], bh[ni], acc[mi][ni], 0, 0, 0);
        acc[mi][ni] = __builtin_amdgcn_mfma_f32_16x16x32_bf16(ah[mi], bl[ni], acc[mi][ni], 0, 0, 0);
      }
  }

  // epilogue; C/D layout: col = l15, row = quad*4 + reg
  const int rb = wm * 64;
  if (MODE == 0 || MODE == 3) {
    float* Cb;
    const float* bp = bias;
    if (MODE == 3) {
      int tl = m0 >> 8;
      Cb = C + (((size_t)dir * CHUNK + tl) * 256 + (m0 & 255)) * (size_t)N;
      bp = bias + (size_t)dir * N;
    } else {
      Cb = C + (size_t)m0 * N;
    }
#pragma unroll
    for (int mi = 0; mi < 4; ++mi)
#pragma unroll
      for (int ni = 0; ni < 4; ++ni) {
        int col = n0 + wn * 64 + ni * 16 + l15;
        float bv = bp[col];
#pragma unroll
        for (int r = 0; r < 4; ++r) {
          int row = rb + mi * 16 + quad * 4 + r;
          Cb[(size_t)row * N + col] = acc[mi][ni][r] + bv;
        }
      }
  } else if (MODE == 1) {
#pragma unroll
    for (int ni = 0; ni < 4; ++ni) {
      int col = n0 + wn * 64 + ni * 16 + l15;
      float bv = bias[col];
      float s = 0.f, q = 0.f;
#pragma unroll
      for (int mi = 0; mi < 4; ++mi)
#pragma unroll
        for (int r = 0; r < 4; ++r) {
          float z = acc[mi][ni][r] + bv;
          s += z;
          q += z * z;
        }
      s += __shfl_xor(s, 16); s += __shfl_xor(s, 32);
      q += __shfl_xor(q, 16); q += __shfl_xor(q, 32);
      if (quad == 0) {
        atomicAdd(&cs[col], s);
        atomicAdd(&csq[col], q);
      }
    }
  } else {  // MODE 2
#pragma unroll
    for (int mi = 0; mi < 4; ++mi) {
      float rv[4] = {0.f, 0.f, 0.f, 0.f};
#pragma unroll
      for (int ni = 0; ni < 4; ++ni) {
        int col = n0 + wn * 64 + ni * 16 + l15;
        float bv = bias[col], mc = bnm[col], ic = bni[col], wc = s2w[col];
#pragma unroll
        for (int r = 0; r < 4; ++r) {
          float z = acc[mi][ni][r] + bv;
          rv[r] += leakyf((z - mc) * ic) * wc;
        }
      }
#pragma unroll
      for (int r = 0; r < 4; ++r) {
        float v = rv[r];
        v += __shfl_xor(v, 1); v += __shfl_xor(v, 2);
        v += __shfl_xor(v, 4); v += __shfl_xor(v, 8);
        if (l15 == 0) atomicAdd(&alpha[m0 + rb + mi * 16 + quad * 4 + r], v);
      }
    }
  }
}

// ---------------- per-step LSTM recurrence kernel (one launch per t) ----------------
// Flat grid of 256 blocks, XCD-group swizzled: group g = id&7 selects (b-tile, dir),
// j-tile = id>>3. Under round-robin dispatch (XCD = id % 8) all 32 blocks of a group
// (the writers AND readers of the same 64-row h slice) land on ONE XCD -> h stays
// L2-local across steps, and each XCD re-reads only its own dir's Whh slice
// (hi+lo = 4 MB = L2 size, resident across all 128 steps). If the HW mapping
// differs, only locality degrades - correctness is mapping-independent.
// Whh tile (4 gates x 16 j) x K=512 hi+lo staged per launch into XOR-swizzled LDS
// (slot' = slot ^ (row&7) -> conflict-free ds_read_b128); single __syncthreads.
// h state packed bf16 hi/lo octet-interleaved in global ([b][64 oct][8 hi + 8 lo]);
// A-fragments = one contiguous 32B read per lane per k-octet, global -> VGPR direct.
// Masked rows (t >= len) write ZEROS to Hseq at ro=t (the pad slot for both dirs),
// replacing the 134 MB Hseq memset.
__global__ __launch_bounds__(256, 1) void k_step(
    const unsigned short* __restrict__ Bhi, const unsigned short* __restrict__ Blo,
    const float* __restrict__ XG, const int* __restrict__ lens,
    unsigned short* __restrict__ Hpk,   // [2par][2dir][BB][64oct][16]
    float* __restrict__ Cst,
    unsigned short* __restrict__ Hhi, unsigned short* __restrict__ Hlo,
    int t) {
  __shared__ unsigned short Bsh[64 * 512];   // 64 KB
  __shared__ unsigned short Bsl[64 * 512];   // 64 KB
  const int tid = threadIdx.x;
  const int id = blockIdx.x;
  const int g = id & 7;                      // XCD group
  const int b0 = (g >> 1) * 64;
  const int dir = g & 1;
  const int j0 = (id >> 3) * 16;
  const int tl = t & (CHUNK - 1);
  const int rpar = t & 1, wpar = (t + 1) & 1;

  const int wave = tid >> 6, lane = tid & 63;
  const int quad = lane >> 4, l15 = lane & 15;
  const int j = j0 + l15;
  const int amrow = b0 + wave * 16 + l15;    // A-frag row this lane reads

  // ---- A-fragment prefetch (packed h state: per octet 8 hi + 8 lo u16 = 32B) ----
  const unsigned short* Ab = Hpk + (((size_t)rpar * 2 + dir) * BB + amrow) * 1024;
  uint4 ahv[16], alv[16];
#pragma unroll
  for (int ks = 0; ks < 16; ++ks) {
    const uint4* p = (const uint4*)Ab + (size_t)(ks * 4 + quad) * 2;
    ahv[ks] = p[0];
    alv[ks] = p[1];
  }

  // ---- epilogue-input prefetch ----
  int bv[4], lenv[4];
  float cstate[4], xgv[4][4];
  size_t sidx[4];
#pragma unroll
  for (int r = 0; r < 4; ++r) {
    bv[r] = b0 + wave * 16 + quad * 4 + r;
    lenv[r] = lens[bv[r]];
    sidx[r] = ((size_t)dir * BB + bv[r]) * HH + j;
    cstate[r] = Cst[sidx[r]];
    size_t xgb = (((size_t)dir * CHUNK + tl) * BB + bv[r]) * (size_t)G4 + j;
#pragma unroll
    for (int gg = 0; gg < 4; ++gg) xgv[r][gg] = XG[xgb + (size_t)gg * HH];
  }

  // ---- stage Whh tile into LDS with 16B-slot XOR swizzle (once per launch) ----
#pragma unroll
  for (int ii = 0; ii < 16; ++ii) {
    int i = ii * 256 + tid;                  // 64 rows x 64 uint4-slots
    int row = i >> 6, s = i & 63;
    int sp = s ^ (row & 7);
    int grow = dir * G4 + (row >> 4) * HH + j0 + (row & 15);  // gate*512 + j
    ((uint4*)Bsh)[row * 64 + sp] = ((const uint4*)(Bhi + (size_t)grow * HH))[s];
    ((uint4*)Bsl)[row * 64 + sp] = ((const uint4*)(Blo + (size_t)grow * HH))[s];
  }
  __syncthreads();

  // ---- K-loop: pure ds_read + MFMA ----
  f4v acc[4];
#pragma unroll
  for (int gg = 0; gg < 4; ++gg) acc[gg] = (f4v){0.f, 0.f, 0.f, 0.f};
#pragma unroll
  for (int ks = 0; ks < 16; ++ks) {
    s8v ah = *(s8v*)&ahv[ks];
    s8v al = *(s8v*)&alv[ks];
#pragma unroll
    for (int gg = 0; gg < 4; ++gg) {
      int row = gg * 16 + l15;
      int sp = (ks * 4 + quad) ^ (l15 & 7);  // row&7 == l15&7
      s8v bh = *(const s8v*)(Bsh + row * 512 + sp * 8);
      s8v bl = *(const s8v*)(Bsl + row * 512 + sp * 8);
      acc[gg] = __builtin_amdgcn_mfma_f32_16x16x32_bf16(ah, bh, acc[gg], 0, 0, 0);
      acc[gg] = __builtin_amdgcn_mfma_f32_16x16x32_bf16(al, bh, acc[gg], 0, 0, 0);
      acc[gg] = __builtin_amdgcn_mfma_f32_16x16x32_bf16(ah, bl, acc[gg], 0, 0, 0);
    }
  }

  // ---- epilogue: fused cell update; packed-split h to write-parity buffer ----
  unsigned short* Wb = Hpk + (((size_t)wpar * 2 + dir) * BB) * 1024;
  const unsigned short* Rb = Hpk + (((size_t)rpar * 2 + dir) * BB) * 1024;
  const int oj = (j >> 3) * 16 + (j & 7);
#pragma unroll
  for (int r = 0; r < 4; ++r) {
    size_t wi = (size_t)bv[r] * 1024 + oj;
    if (t < lenv[r]) {
      float gi = acc[0][r] + xgv[r][0];
      float gf = acc[1][r] + xgv[r][1];
      float gg = acc[2][r] + xgv[r][2];
      float go = acc[3][r] + xgv[r][3];
      float cn = sigmf(gf) * cstate[r] + sigmf(gi) * tanhfast(gg);
      float hn = sigmf(go) * tanhfast(cn);
      Cst[sidx[r]] = cn;
      unsigned hb = __float_as_uint(hn);
      unsigned short h16 = (unsigned short)(hb >> 16);
      unsigned short l16 =
          (unsigned short)(__float_as_uint(hn - __uint_as_float(hb & 0xffff0000u)) >> 16);
      Wb[wi] = h16;
      Wb[wi + 8] = l16;
      int ro = dir ? (lenv[r] - 1 - t) : t;
      size_t hidx = ((size_t)bv[r] * TT + ro) * DD + (size_t)dir * HH + j;
      Hhi[hidx] = h16;
      Hlo[hidx] = l16;
    } else {  // frozen row (t >= len): copy state through; zero the Hseq pad slot (ro = t)
      Wb[wi] = Rb[wi];
      Wb[wi + 8] = Rb[wi + 8];
      size_t hidx = ((size_t)bv[r] * TT + t) * DD + (size_t)dir * HH + j;
      Hhi[hidx] = 0;
      Hlo[hidx] = 0;
    }
  }
}

__global__ __launch_bounds__(256) void k_bnfinal(const float* __restrict__ cs, const float* __restrict__ csq,
                                                 float* __restrict__ bnm, float* __restrict__ bni, float invN) {
  int i = blockIdx.x * 256 + threadIdx.x;
  if (i < DD) {
    float m = cs[i] * invN;
    float v = csq[i] * invN - m * m;
    bnm[i] = m;
    bni[i] = rsqrtf(v + 1e-5f);
  }
}

__global__ __launch_bounds__(128) void k_asum(float* __restrict__ alpha, const int* __restrict__ lens) {
  int b = blockIdx.x;
  int t = threadIdx.x;
  int len = lens[b];
  float v = (t < len) ? alpha[b * TT + t] : 0.f;
  float s = v;
  for (int o = 32; o > 0; o >>= 1) s += __shfl_down(s, o);
  __shared__ float sw[2];
  if ((t & 63) == 0) sw[t >> 6] = s;
  __syncthreads();
  float S = sw[0] + sw[1] + 1e-9f;
  alpha[b * TT + t] = v / S;
}

__global__ __launch_bounds__(256) void k_U(const unsigned short* __restrict__ Hhi,
                                           const unsigned short* __restrict__ Hlo,
                                           const float* __restrict__ alpha,
                                           float* __restrict__ U) {
  int b = blockIdx.x;
  int tid = threadIdx.x;
  __shared__ float al[TT];
  if (tid < TT) al[tid] = alpha[b * TT + tid];
  __syncthreads();
  float4 s = make_float4(0.f, 0.f, 0.f, 0.f);
  size_t base = (size_t)b * TT * DD + tid * 4;
#pragma unroll 4
  for (int t = 0; t < TT; ++t) {
    float a = al[t];
    ushort4 hv = *(const ushort4*)(Hhi + base + (size_t)t * DD);
    ushort4 lv = *(const ushort4*)(Hlo + base + (size_t)t * DD);
    s.x += a * (__uint_as_float((unsigned)hv.x << 16) + __uint_as_float((unsigned)lv.x << 16));
    s.y += a * (__uint_as_float((unsigned)hv.y << 16) + __uint_as_float((unsigned)lv.y << 16));
    s.z += a * (__uint_as_float((unsigned)hv.z << 16) + __uint_as_float((unsigned)lv.z << 16));
    s.w += a * (__uint_as_float((unsigned)hv.w << 16) + __uint_as_float((unsigned)lv.w << 16));
  }
  *(float4*)(U + (size_t)b * DD + tid * 4) = s;
}

__global__ __launch_bounds__(256) void k_p2a(const float* __restrict__ U,
                                             const int* __restrict__ emoI,
                                             const int* __restrict__ cauI,
                                             float* __restrict__ chunkEmb) {
  int e = blockIdx.x;
  int tid = threadIdx.x;
  __shared__ float emoS[DD];
  __shared__ float sc[NCK][16];
  const float* Ue = U + (size_t)emoI[e] * DD;
  for (int i = tid; i < DD; i += 256) emoS[i] = Ue[i];
  __syncthreads();
  int w = tid >> 6, lane = tid & 63;
  for (int p = w; p < 128; p += 4) {
    const float* y = U + (size_t)cauI[p] * DD;
    float s = 0;
    for (int d = lane; d < DD; d += 64) s += emoS[d] * y[d];
    for (int o = 32; o > 0; o >>= 1) s += __shfl_down(s, o);
    if (lane == 0) sc[p >> 4][p & 15] = s;
  }
  __syncthreads();
  if (tid < NCK) {
    float mx = -1e30f;
    for (int c = 0; c < 16; ++c) mx = fmaxf(mx, sc[tid][c]);
    float sum = 0;
    for (int c = 0; c < 16; ++c) {
      float ev = __expf(sc[tid][c] - mx);
      sc[tid][c] = ev;
      sum += ev;
    }
    float inv = 1.f / sum;
    for (int c = 0; c < 16; ++c) sc[tid][c] *= inv;
  }
  __syncthreads();
  int d = tid * 4;
  for (int nn = 0; nn < NCK; ++nn) {
    float4 s = make_float4(0.f, 0.f, 0.f, 0.f);
    for (int c = 0; c < 16; ++c) {
      float wc = sc[nn][c];
      float4 y = *(const float4*)(U + (size_t)cauI[nn * 16 + c] * DD + d);
      s.x += wc * y.x; s.y += wc * y.y; s.z += wc * y.z; s.w += wc * y.w;
    }
    *(float4*)(chunkEmb + ((size_t)e * NCK + nn) * DD + d) = s;
  }
}

__global__ __launch_bounds__(256) void k_delta2(const float* __restrict__ U,
                                                const int* __restrict__ emoI,
                                                const float* __restrict__ chunkEmb,
                                                const float* __restrict__ pos,
                                                float* __restrict__ delta2) {
  int e = blockIdx.x >> 3, nn = blockIdx.x & 7;
  int tid = threadIdx.x;
  const float* emo = U + (size_t)emoI[e] * DD;
  const float* y = chunkEmb + ((size_t)e * NCK + nn) * DD;
  __shared__ float s4[4];
  float ds = 0;
  for (int d = tid; d < DD; d += 256) {
    float df = emo[d] - y[d];
    ds += df * df;
  }
  float dist = sqrtf(blk_sum(ds, s4));
  float* out = delta2 + ((size_t)e * NCK + nn) * K3PAD;
  for (int c = tid; c < K3PAD; c += 256) {
    float v;
    if (c < 1024) v = emo[c];
    else if (c < 2048) v = y[c - 1024];
    else if (c == 2048) v = dist;
    else if (c < 3073) { int d = c - 2049; v = emo[d] * y[d]; }
    else if (c < 3123) v = pos[((size_t)e * NCK + nn) * PPP + (c - 3073)];
    else v = 0.f;
    out[c] = v;
  }
}

__global__ __launch_bounds__(256) void k_bnstats(const float* __restrict__ X,
                                                 float* __restrict__ bm, float* __restrict__ bi, int R) {
  int gid = blockIdx.x * 256 + threadIdx.x;  // NE*DD
  int e = gid >> 10, col = gid & 1023;
  const float* p = X + (size_t)e * R * DD + col;
  float s = 0, s2 = 0;
  for (int r = 0; r < R; ++r) {
    float v = p[(size_t)r * DD];
    s += v;
    s2 += v * v;
  }
  float m = s / R;
  float var = s2 / R - m * m;
  bm[gid] = m;
  bi[gid] = rsqrtf(var + 1e-5f);
}

__global__ __launch_bounds__(256) void k_out2(const float* __restrict__ h2,
                                              const float* __restrict__ bm, const float* __restrict__ bi,
                                              const float* __restrict__ Wo, const float* __restrict__ Wob,
                                              float* __restrict__ out, float* __restrict__ extraf) {
  int e = blockIdx.x >> 3, nn = blockIdx.x & 7;
  int tid = threadIdx.x;
  const float* row = h2 + ((size_t)e * NCK + nn) * DD;
  float l0 = 0, l1 = 0;
  for (int col = tid; col < DD; col += 256) {
    float h = leakyf((row[col] - bm[e * DD + col]) * bi[e * DD + col]);
    l0 += h * Wo[col];
    l1 += h * Wo[DD + col];
  }
  __shared__ float s4[4];
  l0 = blk_sum(l0, s4);
  l1 = blk_sum(l1, s4);
  if (tid == 0) {
    l0 += Wob[0];
    l1 += Wob[1];
    float mx = fmaxf(l0, l1);
    float lse = mx + logf(__expf(l0 - mx) + __expf(l1 - mx));
    out[((size_t)e * NCK + nn) * 2 + 0] = l0 - lse;
    out[((size_t)e * NCK + nn) * 2 + 1] = l1 - lse;
    extraf[e * NCK + nn] = (l1 > l0) ? 1.f : 0.f;
  }
}

__global__ __launch_bounds__(256) void k_delta3(const float* __restrict__ U,
                                                const int* __restrict__ emoI,
                                                const int* __restrict__ cauI,
                                                const float* __restrict__ dis,
                                                const float* __restrict__ extraf,
                                                float* __restrict__ delta3) {
  int e = blockIdx.x >> 7, c = blockIdx.x & 127;
  int tid = threadIdx.x;
  const float* emo = U + (size_t)emoI[e] * DD;
  const float* y = U + (size_t)cauI[c] * DD;
  __shared__ float s4[4];
  float ds = 0;
  for (int d = tid; d < DD; d += 256) {
    float df = emo[d] - y[d];
    ds += df * df;
  }
  float dist = sqrtf(blk_sum(ds, s4));
  float ex = extraf[e * NCK + (c >> 4)];
  float* out = delta3 + ((size_t)e * NCC + c) * K3PAD;
  for (int col = tid; col < K3PAD; col += 256) {
    float v;
    if (col < 1024) v = emo[col];
    else if (col < 2048) v = y[col - 1024];
    else if (col == 2048) v = dist;
    else if (col < 3073) { int d = col - 2049; v = emo[d] * y[d]; }
    else if (col < 3123) v = dis[((size_t)e * NCC + c) * PPP + (col - 3073)];
    else if (col < 3173) v = ex;
    else v = 0.f;
    out[col] = v;
  }
}

__global__ __launch_bounds__(256) void k_p3(const float* __restrict__ h3,
                                            const float* __restrict__ bm, const float* __restrict__ bi,
                                            const float* __restrict__ cw, const float* __restrict__ cb,
                                            float* __restrict__ out) {
  int e = blockIdx.x >> 7, c = blockIdx.x & 127;
  int tid = threadIdx.x;
  const float* row = h3 + ((size_t)e * NCC + c) * DD;
  float l0 = 0, l1 = 0;
  for (int col = tid; col < DD; col += 256) {
    float h = leakyf((row[col] - bm[e * DD + col]) * bi[e * DD + col]);
    l0 += h * cw[col];
    l1 += h * cw[DD + col];
  }
  __shared__ float s4[4];
  l0 = blk_sum(l0, s4);
  l1 = blk_sum(l1, s4);
  if (tid == 0) {
    l0 += cb[0];
    l1 += cb[1];
    float mx = fmaxf(l0, l1);
    float lse = mx + logf(__expf(l0 - mx) + __expf(l1 - mx));
    out[((size_t)e * NCC + c) * 2 + 0] = l0 - lse;
    out[((size_t)e * NCC + c) * 2 + 1] = l1 - lse;
  }
}

__global__ __launch_bounds__(256) void k_L(const int* __restrict__ lab, float* __restrict__ out) {
  int i = blockIdx.x * 256 + threadIdx.x;  // 8192
  int e = i >> 7, c = i & 127;
  int a = lab[e * 3 + 0], b = lab[e * 3 + 1], d = lab[e * 3 + 2];
  out[i] = (a == c || b == c || d == c) ? 1.f : 0.f;
}

extern "C" void kernel_launch(void* const* d_in, const int* in_sizes, int n_in,
                              void* d_out, int out_size, void* d_ws, size_t ws_size,
                              hipStream_t stream) {
  (void)in_sizes; (void)n_in; (void)out_size; (void)ws_size;
  const float* X     = (const float*)d_in[0];
  const float* pos   = (const float*)d_in[1];
  const float* dis   = (const float*)d_in[2];
  const int*   lens  = (const int*)d_in[3];
  const int*   lab3  = (const int*)d_in[4];
  const int*   emoI  = (const int*)d_in[5];
  const int*   cauI  = (const int*)d_in[6];
  const float* Wih_f = (const float*)d_in[7];
  const float* Whh_f = (const float*)d_in[8];
  const float* bih_f = (const float*)d_in[9];
  const float* bhh_f = (const float*)d_in[10];
  const float* Wih_b = (const float*)d_in[11];
  const float* Whh_b = (const float*)d_in[12];
  const float* bih_b = (const float*)d_in[13];
  const float* bhh_b = (const float*)d_in[14];
  const float* s1w   = (const float*)d_in[15];
  const float* s1b   = (const float*)d_in[16];
  const float* s2w   = (const float*)d_in[17];
  const float* W2w   = (const float*)d_in[18];
  const float* W2b   = (const float*)d_in[19];
  const float* Wow   = (const float*)d_in[20];
  const float* Wob   = (const float*)d_in[21];
  const float* W3w   = (const float*)d_in[22];
  const float* W3b   = (const float*)d_in[23];
  const float* clsw  = (const float*)d_in[24];
  const float* clsb  = (const float*)d_in[25];
  float* ws = (float*)d_ws;
  float* out = (float*)d_out;

  unsigned short* Hhi = (unsigned short*)(ws + F_HSEQ);
  unsigned short* Hlo = Hhi + (size_t)NROWS * DD;
  unsigned short* WIHhi = (unsigned short*)(ws + F_WIH);
  unsigned short* WIHlo = WIHhi + (size_t)2 * 2048 * 1024;
  unsigned short* WHHhi = (unsigned short*)(ws + F_WHH);
  unsigned short* WHHlo = WHHhi + (size_t)2 * 2048 * 512;
  unsigned short* S1hi  = (unsigned short*)(ws + F_S1);
  unsigned short* S1lo  = S1hi + (size_t)1024 * 1024;
  unsigned short* W2hi  = (unsigned short*)(ws + F_W2);
  unsigned short* W2lo  = W2hi + (size_t)1024 * K3PAD;
  unsigned short* W3hi  = (unsigned short*)(ws + F_W3);
  unsigned short* W3lo  = W3hi + (size_t)1024 * K3PAD;
  unsigned short* Hpk   = (unsigned short*)(ws + F_HST);   // [2par][2dir][256][64oct][16]

  // zero-init read-before-write buffers. NOTE: the 134 MB Hseq memset is GONE -
  // k_step's masked branch zero-fills the pad rows (ro = t for t >= len, both dirs),
  // and every (b,t) slot is written exactly once per invocation.
  hipMemsetAsync(ws + F_HST, 0, (size_t)(524288 + 262144) * sizeof(float), stream);  // Hpk + CST
  hipMemsetAsync(ws + F_CS, 0, (size_t)2048 * sizeof(float), stream);                // CS + CSQ
  hipMemsetAsync(ws + F_ALPHA, 0, (size_t)32768 * sizeof(float), stream);

  // weight converts (fp32 -> bf16 hi/lo, n-major = native torch layout)
  k_cvt<<<2048, 256, 0, stream>>>(Wih_f, WIHhi, WIHlo, 1024, 1024);
  k_cvt<<<2048, 256, 0, stream>>>(Wih_b, WIHhi + (size_t)2048 * 1024, WIHlo + (size_t)2048 * 1024, 1024, 1024);
  k_cvt<<<2048, 256, 0, stream>>>(Whh_f, WHHhi, WHHlo, 512, 512);
  k_cvt<<<2048, 256, 0, stream>>>(Whh_b, WHHhi + (size_t)2048 * 512, WHHlo + (size_t)2048 * 512, 512, 512);
  k_cvt<<<1024, 256, 0, stream>>>(s1w, S1hi, S1lo, 1024, 1024);
  k_cvt<<<1024, 256, 0, stream>>>(W2w, W2hi, W2lo, 3123, K3PAD);
  k_cvt<<<1024, 256, 0, stream>>>(W3w, W3hi, W3lo, 3173, K3PAD);
  k_biasc<<<16, 256, 0, stream>>>(bih_f, bhh_f, bih_b, bhh_b, ws + F_BIASC);

  // BiLSTM: chunked input-projection MFMA GEMMs + per-step fused recurrence
  for (int c = 0; c < TT / CHUNK; ++c) {
    k_mf<3><<<dim3(16, 16, 2), 256, 0, stream>>>(X, nullptr, nullptr, WIHhi, WIHlo,
                                                 ws + F_BIASC, ws + F_XG,
                                                 2048, 2048, 1024, lens, c,
                                                 nullptr, nullptr, nullptr, nullptr, nullptr, nullptr);
    for (int tt = 0; tt < CHUNK; ++tt) {
      int t = c * CHUNK + tt;
      k_step<<<dim3(256), 256, 0, stream>>>(WHHhi, WHHlo, ws + F_XG, lens,
                                            Hpk, ws + F_CST, Hhi, Hlo, t);
    }
  }

  // attention: two-pass z (BN stats, then masked-linear attention weights); A pre-split
  k_mf<1><<<dim3(256, 8), 256, 0, stream>>>(nullptr, Hhi, Hlo, S1hi, S1lo, s1b, nullptr,
                                            NROWS, 1024, 1024, nullptr, 0,
                                            nullptr, nullptr, nullptr,
                                            ws + F_CS, ws + F_CSQ, nullptr);
  k_bnfinal<<<4, 256, 0, stream>>>(ws + F_CS, ws + F_CSQ, ws + F_BNM, ws + F_BNI, 1.f / NROWS);
  k_mf<2><<<dim3(256, 8), 256, 0, stream>>>(nullptr, Hhi, Hlo, S1hi, S1lo, s1b, nullptr,
                                            NROWS, 1024, 1024, nullptr, 0,
                                            ws + F_BNM, ws + F_BNI, s2w,
                                            nullptr, nullptr, ws + F_ALPHA);
  k_asum<<<BB, TT, 0, stream>>>(ws + F_ALPHA, lens);
  k_U<<<BB, 256, 0, stream>>>(Hhi, Hlo, ws + F_ALPHA, ws + F_U);

  // phase 2 (D2/CHE overlay dead Hseq region)
  k_p2a<<<NE, 256, 0, stream>>>(ws + F_U, emoI, cauI, ws + F_CHE);
  k_delta2<<<NE * NCK, 256, 0, stream>>>(ws + F_U, emoI, ws + F_CHE, pos, ws + F_D2);
  k_mf<0><<<dim3(4, 8), 256, 0, stream>>>(ws + F_D2, nullptr, nullptr, W2hi, W2lo, W2b, ws + F_H2,
                                          512, 1024, K3PAD, nullptr, 0,
                                          nullptr, nullptr, nullptr, nullptr, nullptr, nullptr);
  k_bnstats<<<256, 256, 0, stream>>>(ws + F_H2, ws + F_BN2M, ws + F_BN2I, NCK);
  k_out2<<<NE * NCK, 256, 0, stream>>>(ws + F_H2, ws + F_BN2M, ws + F_BN2I, Wow, Wob,
                                       out, ws + F_EXTRA);

  // phase 3 (D3 overlays Hseq; H3 overlays dead XG)
  k_delta3<<<NE * NCC, 256, 0, stream>>>(ws + F_U, emoI, cauI, dis, ws + F_EXTRA, ws + F_D3);
  k_mf<0><<<dim3(64, 8), 256, 0, stream>>>(ws + F_D3, nullptr, nullptr, W3hi, W3lo, W3b, ws + F_H3,
                                           8192, 1024, K3PAD, nullptr, 0,
                                           nullptr, nullptr, nullptr, nullptr, nullptr, nullptr);
  k_bnstats<<<256, 256, 0, stream>>>(ws + F_H3, ws + F_BN3M, ws + F_BN3I, NCC);
  k_p3<<<NE * NCC, 256, 0, stream>>>(ws + F_H3, ws + F_BN3M, ws + F_BN3I, clsw, clsb, out + 1024);
  k_L<<<32, 256, 0, stream>>>(lab3, out + 17408);
}

// Round 4
// 3889.554 us; speedup vs baseline: 1.3739x; 1.0357x over previous
//
#include <hip/hip_runtime.h>
#include <math.h>

// ---------------- problem dims ----------------
#define DD    1024
#define TT    128
#define BB    256
#define NE    64
#define NCC   128
#define PPP   50
#define NCK   8
#define HH    512
#define G4    2048     // 4*HH
#define NROWS 32768    // BB*TT
#define K3PAD 3200     // padded K for phase2 GEMM (3123 -> 3200)
#define KP3   1088     // phase-3 P GEMM K: 1024 (emo*y) + 50 (dis) + dist + ex + pad
#define CHUNK 8        // timesteps per XG chunk

// ---------------- workspace layout (float offsets) ----------------
#define F_HSEQ  0ull            // Hseq hi [32768][1024] u16 + lo (33,554,432 float-slots); later D2/CHE
#define F_XG    33554432ull     // [2][CHUNK][256][2048] fp32 8,388,608 ; later H3
#define F_WIH   41943040ull     // bf16 hi[2][2048][1024] + lo  (4,194,304 float-slots)
#define F_WHH   46137344ull     // bf16 hi[2][2048][512] + lo   (2,097,152)
#define F_S1    48234496ull     // bf16 hi[1024][1024] + lo     (1,048,576)
#define F_W2    49283072ull     // bf16 hi[1024][3200] + lo     (3,276,800)
#define F_W3    52559872ull     // W3AB hi/lo [2048][1024] (2,097,152) + W3P hi/lo [1024][1088] (1,114,112)
#define F_BIASC 56885248ull     // [2][2048]
#define F_HST   56889344ull     // packed h state [2par][2dir][256][64oct][16] u16 = 524,288 float-slots
#define F_CST   57413632ull     // [2][256][512] = 262,144
#define F_CS    57675776ull
#define F_CSQ   57676800ull
#define F_BNM   57677824ull
#define F_BNI   57678848ull
#define F_ALPHA 57679872ull     // [BB*TT]; later dist[8192]
#define F_U     57712640ull     // [BB,DD] 262,144
#define F_H2    57974784ull     // [64,8,1024] 524,288 ; later E3Y3 [256][2048]
#define F_BN2M  58499072ull
#define F_BN2I  58564608ull
#define F_EXTRA 58630144ull
#define F_BN3M  58631168ull
#define F_BN3I  58696704ull
#define F_GIDX  58762240ull     // 256 ints

#define F_D2    F_HSEQ
#define F_CHE   (F_HSEQ + 26214400ull)
#define F_H3    F_XG

typedef short s8v __attribute__((ext_vector_type(8)));
typedef float f4v __attribute__((ext_vector_type(4)));

__device__ __forceinline__ float leakyf(float x) { return x >= 0.f ? x : 0.01f * x; }
__device__ __forceinline__ float sigmf(float x)  { return 1.f / (1.f + __expf(-x)); }
__device__ __forceinline__ float tanhfast(float x) {
  float e = __expf(2.f * x);
  return 1.f - 2.f / (e + 1.f);
}

__device__ __forceinline__ float blk_sum(float v, float* s4) {
  for (int o = 32; o > 0; o >>= 1) v += __shfl_down(v, o);
  __syncthreads();
  if ((threadIdx.x & 63) == 0) s4[threadIdx.x >> 6] = v;
  __syncthreads();
  return s4[0] + s4[1] + s4[2] + s4[3];
}

// pack 2 fp32 -> (hi bf16 pair, lo bf16 pair); hi = truncation, lo = exact residual truncated
__device__ __forceinline__ void cvt2(float x0, float x1, unsigned& hi, unsigned& lo) {
  unsigned b0 = __float_as_uint(x0), b1 = __float_as_uint(x1);
  hi = (b0 >> 16) | (b1 & 0xffff0000u);
  float h0 = __uint_as_float(b0 & 0xffff0000u);
  float h1 = __uint_as_float(b1 & 0xffff0000u);
  unsigned l0 = __float_as_uint(x0 - h0);
  unsigned l1 = __float_as_uint(x1 - h1);
  lo = (l0 >> 16) | (l1 & 0xffff0000u);
}

// weight convert: src fp32 [N][Sstride] cols [off, off+Ks) -> hi/lo bf16 [N][Kd] (zero-padded)
__global__ __launch_bounds__(256) void k_cvt(const float* __restrict__ src,
                                             unsigned short* __restrict__ hi,
                                             unsigned short* __restrict__ lo,
                                             int Ks, int Kd, int Sstride, int off) {
  int n = blockIdx.x;
  for (int k = threadIdx.x; k < Kd; k += 256) {
    float v = (k < Ks) ? src[(size_t)n * Sstride + off + k] : 0.f;
    unsigned b = __float_as_uint(v);
    float h = __uint_as_float(b & 0xffff0000u);
    hi[(size_t)n * Kd + k] = (unsigned short)(b >> 16);
    lo[(size_t)n * Kd + k] = (unsigned short)(__float_as_uint(v - h) >> 16);
  }
}

// W3 "P" operand: [1024 out][KP3]: k<1024 -> W3[o][2049+k] (emo*y); k<1074 -> W3[o][3073+(k-1024)] (dis);
// k==1074 -> W3[o][2048] (dist); k==1075 -> sum W3[o][3123..3172] (ex); else 0
__global__ __launch_bounds__(256) void k_cvtp(const float* __restrict__ src,
                                              unsigned short* __restrict__ hi,
                                              unsigned short* __restrict__ lo) {
  int o = blockIdx.x;
  const float* s = src + (size_t)o * 3173;
  for (int k = threadIdx.x; k < KP3; k += 256) {
    float v;
    if (k < 1024) v = s[2049 + k];
    else if (k < 1074) v = s[3073 + (k - 1024)];
    else if (k == 1074) v = s[2048];
    else if (k == 1075) { float a = 0.f; for (int p = 0; p < 50; ++p) a += s[3123 + p]; v = a; }
    else v = 0.f;
    unsigned b = __float_as_uint(v);
    float h = __uint_as_float(b & 0xffff0000u);
    hi[(size_t)o * KP3 + k] = (unsigned short)(b >> 16);
    lo[(size_t)o * KP3 + k] = (unsigned short)(__float_as_uint(v - h) >> 16);
  }
}

__global__ __launch_bounds__(256) void k_biasc(const float* __restrict__ bf1, const float* __restrict__ bf2,
                                               const float* __restrict__ bb1, const float* __restrict__ bb2,
                                               float* __restrict__ out) {
  int i = blockIdx.x * 256 + threadIdx.x;  // 4096
  if (i < G4) out[i] = bf1[i] + bf2[i];
  else        out[i] = bb1[i - G4] + bb2[i - G4];
}

__global__ __launch_bounds__(256) void k_gidx(const int* __restrict__ emoI, const int* __restrict__ cauI,
                                              int* __restrict__ g) {
  int i = threadIdx.x;  // 256
  g[i] = (i < 64) ? emoI[i] : (i < 192 ? cauI[i - 64] : 0);
}

// dist[e*NCC+c] = || U[emoI[e]] - U[cauI[c]] ||
__global__ __launch_bounds__(256) void k_dist(const float* __restrict__ U,
                                              const int* __restrict__ emoI, const int* __restrict__ cauI,
                                              float* __restrict__ dist) {
  int e = blockIdx.x >> 7, c = blockIdx.x & 127;
  int tid = threadIdx.x;
  const float* emo = U + (size_t)emoI[e] * DD;
  const float* y = U + (size_t)cauI[c] * DD;
  __shared__ float s4[4];
  float ds = 0;
  for (int d = tid; d < DD; d += 256) {
    float df = emo[d] - y[d];
    ds += df * df;
  }
  float dd = blk_sum(ds, s4);
  if (tid == 0) dist[blockIdx.x] = sqrtf(dd);
}

// ---------------- MFMA GEMM, 128x128 tile, split-bf16 3-term (fp32-accurate) ----------------
// B bf16 hi/lo n-major [N][K].
// MODE 0 STORE: A fp32; C = A@B + bias                         (p2 GEMM)
// MODE 1 STATS: A pre-split hi/lo; atomic col sum/sumsq        (z pass 1)
// MODE 2 ALPHA: A pre-split hi/lo; atomic row sum of leaky((z-bnm)*bni)*s2w  (z pass 2)
// MODE 3 XG:    A fp32 rows gathered from X via lens; dir = blockIdx.z
// MODE 5 P3:    A synthesized on the fly: [emo*y | dis | dist | ex | 0]; C = acc + E3 + Y3 + b3
// MODE 6 GATH:  A fp32 rows gathered via gi1; C = acc (no bias)
template <int MODE>
__global__ __launch_bounds__(256, 2) void k_mf(
    const float* __restrict__ A,
    const unsigned short* __restrict__ Ahi, const unsigned short* __restrict__ Alo,
    const unsigned short* __restrict__ Bhi, const unsigned short* __restrict__ Blo,
    const float* __restrict__ bias, float* __restrict__ C, int M, int N, int K,
    const int* __restrict__ lens, int c,
    const float* __restrict__ bnm, const float* __restrict__ bni,
    const float* __restrict__ s2w, float* __restrict__ cs,
    float* __restrict__ csq, float* __restrict__ alpha,
    const int* __restrict__ gi1, const int* __restrict__ gi2,
    const float* __restrict__ aux1, const float* __restrict__ aux2) {
  __shared__ unsigned short Ah[128][40];
  __shared__ unsigned short Al[128][40];
  __shared__ unsigned short Bh[128][40];
  __shared__ unsigned short Bl[128][40];
  const int tid = threadIdx.x;
  const int m0 = blockIdx.x * 128;
  const int n0 = blockIdx.y * 128;
  const int dir = (MODE == 3) ? blockIdx.z : 0;

  const int sr = tid >> 1;
  const int sh = tid & 1;
  const float* arow = nullptr;
  const unsigned short* ahrow = nullptr;
  const unsigned short* alrow = nullptr;
  const float* emo5 = nullptr;
  const float* y5 = nullptr;
  if (MODE == 3) {
    int tl = m0 >> 8;
    int b = (m0 & 255) + sr;
    int t = c * CHUNK + tl;
    int len = lens[b];
    int r = (dir == 0) ? t : ((t < len) ? (len - 1 - t) : t);
    arow = A + ((size_t)b * TT + r) * DD;
  } else if (MODE == 0) {
    arow = A + (size_t)(m0 + sr) * K;
  } else if (MODE == 6) {
    arow = A + (size_t)gi1[m0 + sr] * K;
  } else if (MODE == 5) {
    emo5 = A + (size_t)gi1[blockIdx.x] * DD;   // e = blockIdx.x (M=8192, 128 rows/block)
    y5   = A + (size_t)gi2[sr] * DD;           // c = sr
  } else {
    ahrow = Ahi + (size_t)(m0 + sr) * K;
    alrow = Alo + (size_t)(m0 + sr) * K;
  }
  const unsigned short* bhrow = Bhi + ((size_t)dir * N + n0 + sr) * K;
  const unsigned short* blrow = Blo + ((size_t)dir * N + n0 + sr) * K;

  const int wave = tid >> 6, lane = tid & 63;
  const int wm = wave & 1, wn = wave >> 1;
  const int quad = lane >> 4, l15 = lane & 15;

  f4v acc[4][4];
#pragma unroll
  for (int i = 0; i < 4; ++i)
#pragma unroll
    for (int j = 0; j < 4; ++j) acc[i][j] = (f4v){0.f, 0.f, 0.f, 0.f};

#pragma unroll 1
  for (int k0 = 0; k0 < K; k0 += 32) {
    __syncthreads();
    if (MODE == 1 || MODE == 2) {
      const uint4* ph = (const uint4*)(ahrow + k0 + sh * 16);
      uint4* dh = (uint4*)&Ah[sr][sh * 16];
      dh[0] = ph[0]; dh[1] = ph[1];
      const uint4* pl = (const uint4*)(alrow + k0 + sh * 16);
      uint4* dl = (uint4*)&Al[sr][sh * 16];
      dl[0] = pl[0]; dl[1] = pl[1];
    } else if (MODE == 5) {
      unsigned h[8], l[8];
      if (k0 < 1024) {
        const float4* pe = (const float4*)(emo5 + k0 + sh * 16);
        const float4* py = (const float4*)(y5 + k0 + sh * 16);
        float4 a0 = pe[0], a1 = pe[1], a2 = pe[2], a3 = pe[3];
        float4 b0 = py[0], b1 = py[1], b2 = py[2], b3 = py[3];
        cvt2(a0.x * b0.x, a0.y * b0.y, h[0], l[0]); cvt2(a0.z * b0.z, a0.w * b0.w, h[1], l[1]);
        cvt2(a1.x * b1.x, a1.y * b1.y, h[2], l[2]); cvt2(a1.z * b1.z, a1.w * b1.w, h[3], l[3]);
        cvt2(a2.x * b2.x, a2.y * b2.y, h[4], l[4]); cvt2(a2.z * b2.z, a2.w * b2.w, h[5], l[5]);
        cvt2(a3.x * b3.x, a3.y * b3.y, h[6], l[6]); cvt2(a3.z * b3.z, a3.w * b3.w, h[7], l[7]);
      } else {
        float v[16];
#pragma unroll
        for (int i = 0; i < 16; ++i) {
          int k = k0 + sh * 16 + i;
          float val;
          if (k < 1074)      val = s2w[((size_t)blockIdx.x * NCC + sr) * PPP + (k - 1024)];  // dis
          else if (k == 1074) val = aux1[blockIdx.x * NCC + sr];                             // dist
          else if (k == 1075) val = aux2[blockIdx.x * NCK + (sr >> 4)];                      // ex
          else               val = 0.f;
          v[i] = val;
        }
#pragma unroll
        for (int i = 0; i < 8; ++i) cvt2(v[2 * i], v[2 * i + 1], h[i], l[i]);
      }
      uint4* dh = (uint4*)&Ah[sr][sh * 16];
      dh[0] = make_uint4(h[0], h[1], h[2], h[3]);
      dh[1] = make_uint4(h[4], h[5], h[6], h[7]);
      uint4* dl = (uint4*)&Al[sr][sh * 16];
      dl[0] = make_uint4(l[0], l[1], l[2], l[3]);
      dl[1] = make_uint4(l[4], l[5], l[6], l[7]);
    } else {
      const float4* pa = (const float4*)(arow + k0 + sh * 16);
      float4 v0 = pa[0], v1 = pa[1], v2 = pa[2], v3 = pa[3];
      unsigned h[8], l[8];
      cvt2(v0.x, v0.y, h[0], l[0]); cvt2(v0.z, v0.w, h[1], l[1]);
      cvt2(v1.x, v1.y, h[2], l[2]); cvt2(v1.z, v1.w, h[3], l[3]);
      cvt2(v2.x, v2.y, h[4], l[4]); cvt2(v2.z, v2.w, h[5], l[5]);
      cvt2(v3.x, v3.y, h[6], l[6]); cvt2(v3.z, v3.w, h[7], l[7]);
      uint4* dh = (uint4*)&Ah[sr][sh * 16];
      dh[0] = make_uint4(h[0], h[1], h[2], h[3]);
      dh[1] = make_uint4(h[4], h[5], h[6], h[7]);
      uint4* dl = (uint4*)&Al[sr][sh * 16];
      dl[0] = make_uint4(l[0], l[1], l[2], l[3]);
      dl[1] = make_uint4(l[4], l[5], l[6], l[7]);
    }
    {
      const uint4* pbh = (const uint4*)(bhrow + k0 + sh * 16);
      uint4* dbh = (uint4*)&Bh[sr][sh * 16];
      dbh[0] = pbh[0]; dbh[1] = pbh[1];
      const uint4* pbl = (const uint4*)(blrow + k0 + sh * 16);
      uint4* dbl = (uint4*)&Bl[sr][sh * 16];
      dbl[0] = pbl[0]; dbl[1] = pbl[1];
    }
    __syncthreads();
    s8v ah[4], al[4], bh[4], bl[4];
#pragma unroll
    for (int mi = 0; mi < 4; ++mi) {
      ah[mi] = *(const s8v*)&Ah[wm * 64 + mi * 16 + l15][quad * 8];
      al[mi] = *(const s8v*)&Al[wm * 64 + mi * 16 + l15][quad * 8];
    }
#pragma unroll
    for (int ni = 0; ni < 4; ++ni) {
      bh[ni] = *(const s8v*)&Bh[wn * 64 + ni * 16 + l15][quad * 8];
      bl[ni] = *(const s8v*)&Bl[wn * 64 + ni * 16 + l15][quad * 8];
    }
#pragma unroll
    for (int mi = 0; mi < 4; ++mi)
#pragma unroll
      for (int ni = 0; ni < 4; ++ni) {
        acc[mi][ni] = __builtin_amdgcn_mfma_f32_16x16x32_bf16(ah[mi], bh[ni], acc[mi][ni], 0, 0, 0);
        acc[mi][ni] = __builtin_amdgcn_mfma_f32_16x16x32_bf16(al[mi], bh[ni], acc[mi][ni], 0, 0, 0);
        acc[mi][ni] = __builtin_amdgcn_mfma_f32_16x16x32_bf16(ah[mi], bl[ni], acc[mi][ni], 0, 0, 0);
      }
  }

  // epilogue; C/D layout: col = l15, row = quad*4 + reg
  const int rb = wm * 64;
  if (MODE == 0 || MODE == 3 || MODE == 6) {
    float* Cb;
    const float* bp = bias;
    if (MODE == 3) {
      int tl = m0 >> 8;
      Cb = C + (((size_t)dir * CHUNK + tl) * 256 + (m0 & 255)) * (size_t)N;
      bp = bias + (size_t)dir * N;
    } else {
      Cb = C + (size_t)m0 * N;
    }
#pragma unroll
    for (int mi = 0; mi < 4; ++mi)
#pragma unroll
      for (int ni = 0; ni < 4; ++ni) {
        int col = n0 + wn * 64 + ni * 16 + l15;
        float bv = (MODE == 6) ? 0.f : bp[col];
#pragma unroll
        for (int r = 0; r < 4; ++r) {
          int row = rb + mi * 16 + quad * 4 + r;
          Cb[(size_t)row * N + col] = acc[mi][ni][r] + bv;
        }
      }
  } else if (MODE == 5) {
    // C = acc + E3[e] + Y3[c] + b3 ; bias=E3 base (stride 2048), bnm=Y3 base (stride 2048), bni=b3
    float* Cb = C + (size_t)m0 * N;
    int e5 = blockIdx.x;
#pragma unroll
    for (int mi = 0; mi < 4; ++mi)
#pragma unroll
      for (int ni = 0; ni < 4; ++ni) {
        int col = n0 + wn * 64 + ni * 16 + l15;
        float ev = bias[(size_t)e5 * 2048 + col] + bni[col];
#pragma unroll
        for (int r = 0; r < 4; ++r) {
          int row = rb + mi * 16 + quad * 4 + r;
          Cb[(size_t)row * N + col] = acc[mi][ni][r] + ev + bnm[(size_t)row * 2048 + col];
        }
      }
  } else if (MODE == 1) {
#pragma unroll
    for (int ni = 0; ni < 4; ++ni) {
      int col = n0 + wn * 64 + ni * 16 + l15;
      float bv = bias[col];
      float s = 0.f, q = 0.f;
#pragma unroll
      for (int mi = 0; mi < 4; ++mi)
#pragma unroll
        for (int r = 0; r < 4; ++r) {
          float z = acc[mi][ni][r] + bv;
          s += z;
          q += z * z;
        }
      s += __shfl_xor(s, 16); s += __shfl_xor(s, 32);
      q += __shfl_xor(q, 16); q += __shfl_xor(q, 32);
      if (quad == 0) {
        atomicAdd(&cs[col], s);
        atomicAdd(&csq[col], q);
      }
    }
  } else {  // MODE 2
#pragma unroll
    for (int mi = 0; mi < 4; ++mi) {
      float rv[4] = {0.f, 0.f, 0.f, 0.f};
#pragma unroll
      for (int ni = 0; ni < 4; ++ni) {
        int col = n0 + wn * 64 + ni * 16 + l15;
        float bv = bias[col], mc = bnm[col], ic = bni[col], wc = s2w[col];
#pragma unroll
        for (int r = 0; r < 4; ++r) {
          float z = acc[mi][ni][r] + bv;
          rv[r] += leakyf((z - mc) * ic) * wc;
        }
      }
#pragma unroll
      for (int r = 0; r < 4; ++r) {
        float v = rv[r];
        v += __shfl_xor(v, 1); v += __shfl_xor(v, 2);
        v += __shfl_xor(v, 4); v += __shfl_xor(v, 8);
        if (l15 == 0) atomicAdd(&alpha[m0 + rb + mi * 16 + quad * 4 + r], v);
      }
    }
  }
}

// ---------------- per-step LSTM recurrence kernel (one launch per t, K-split) ----------------
// Flat grid 256 blocks, XCD-group decode: g = id&7 -> (b-tile, dir); j-tile = id>>3.
// K=512 split across the 4 waves (128 each): each wave reads its B fragments DIRECTLY
// from global (L2/XCD-resident Whh; B has only 4x block-level reuse, so the LDS
// round-trip bought nothing) and computes a full 64x64 partial tile; a 64 KB
// conflict-free LDS all-reduce combines the 4 partials. One barrier total.
// h state packed bf16 hi/lo octet-interleaved ([b][64 oct][8 hi + 8 lo]).
// Masked rows (t >= len) write ZEROS to Hseq at ro=t (pad slot for both dirs).
__global__ __launch_bounds__(256, 1) void k_step(
    const unsigned short* __restrict__ Bhi, const unsigned short* __restrict__ Blo,
    const float* __restrict__ XG, const int* __restrict__ lens,
    unsigned short* __restrict__ Hpk,   // [2par][2dir][BB][64oct][16]
    float* __restrict__ Cst,
    unsigned short* __restrict__ Hhi, unsigned short* __restrict__ Hlo,
    int t) {
  __shared__ f4v Red[4][4][4][64];   // [src wave][mi][gate][lane] = 64 KB
  const int tid = threadIdx.x;
  const int id = blockIdx.x;
  const int g7 = id & 7;
  const int b0 = (g7 >> 1) * 64;
  const int dir = g7 & 1;
  const int j0 = (id >> 3) * 16;
  const int tl = t & (CHUNK - 1);
  const int rpar = t & 1, wpar = (t + 1) & 1;

  const int wave = tid >> 6, lane = tid & 63;
  const int quad = lane >> 4, l15 = lane & 15;
  const int j = j0 + l15;
  const int kb = wave * 128;                 // this wave's K-slice base

  // ---- B fragments direct from global: row = dir*G4 + gate*HH + j, k = kb + ks*32 + quad*8 ----
  uint4 bhv[4][4], blv[4][4];                // [gate][ks]
#pragma unroll
  for (int g = 0; g < 4; ++g) {
    size_t base = ((size_t)(dir * G4 + g * HH + j)) * HH + kb + quad * 8;
#pragma unroll
    for (int ks = 0; ks < 4; ++ks) {
      bhv[g][ks] = *(const uint4*)(Bhi + base + ks * 32);
      blv[g][ks] = *(const uint4*)(Blo + base + ks * 32);
    }
  }

  // ---- A fragments: rows b0+mi*16+l15, octet = wave*16 + ks*4 + quad ----
  const unsigned short* Ab = Hpk + (((size_t)rpar * 2 + dir) * BB) * 1024;
  uint4 ahv[4][4], alv[4][4];                // [mi][ks]
#pragma unroll
  for (int mi = 0; mi < 4; ++mi) {
    const uint4* arow = (const uint4*)(Ab + (size_t)(b0 + mi * 16 + l15) * 1024)
                        + (size_t)(wave * 16 + quad) * 2;
#pragma unroll
    for (int ks = 0; ks < 4; ++ks) {
      ahv[mi][ks] = arow[ks * 8];
      alv[mi][ks] = arow[ks * 8 + 1];
    }
  }

  // ---- epilogue-input prefetch ----
  int bv[4], lenv[4];
  float cstate[4], xgv[4][4];
  size_t sidx[4];
#pragma unroll
  for (int r = 0; r < 4; ++r) {
    bv[r] = b0 + wave * 16 + quad * 4 + r;
    lenv[r] = lens[bv[r]];
    sidx[r] = ((size_t)dir * BB + bv[r]) * HH + j;
    cstate[r] = Cst[sidx[r]];
    size_t xgb = (((size_t)dir * CHUNK + tl) * BB + bv[r]) * (size_t)G4 + j;
#pragma unroll
    for (int gg = 0; gg < 4; ++gg) xgv[r][gg] = XG[xgb + (size_t)gg * HH];
  }

  // ---- K-slice MFMA: full 64x64 partial tile per wave ----
  f4v acc[4][4];                             // [mi][gate]
#pragma unroll
  for (int mi = 0; mi < 4; ++mi)
#pragma unroll
    for (int gg = 0; gg < 4; ++gg) acc[mi][gg] = (f4v){0.f, 0.f, 0.f, 0.f};
#pragma unroll
  for (int ks = 0; ks < 4; ++ks)
#pragma unroll
    for (int mi = 0; mi < 4; ++mi) {
      s8v ah = *(s8v*)&ahv[mi][ks];
      s8v al = *(s8v*)&alv[mi][ks];
#pragma unroll
      for (int gg = 0; gg < 4; ++gg) {
        s8v bh = *(s8v*)&bhv[gg][ks];
        s8v bl = *(s8v*)&blv[gg][ks];
        acc[mi][gg] = __builtin_amdgcn_mfma_f32_16x16x32_bf16(ah, bh, acc[mi][gg], 0, 0, 0);
        acc[mi][gg] = __builtin_amdgcn_mfma_f32_16x16x32_bf16(al, bh, acc[mi][gg], 0, 0, 0);
        acc[mi][gg] = __builtin_amdgcn_mfma_f32_16x16x32_bf16(ah, bl, acc[mi][gg], 0, 0, 0);
      }
    }

  // ---- cross-wave reduce (conflict-free: contiguous f4v per lane) ----
#pragma unroll
  for (int mi = 0; mi < 4; ++mi)
#pragma unroll
    for (int gg = 0; gg < 4; ++gg) Red[wave][mi][gg][lane] = acc[mi][gg];
  __syncthreads();
  f4v fac[4];
#pragma unroll
  for (int gg = 0; gg < 4; ++gg)
    fac[gg] = Red[0][wave][gg][lane] + Red[1][wave][gg][lane] +
              Red[2][wave][gg][lane] + Red[3][wave][gg][lane];

  // ---- epilogue: fused cell update; packed-split h to write-parity buffer ----
  unsigned short* Wb = Hpk + (((size_t)wpar * 2 + dir) * BB) * 1024;
  const unsigned short* Rb = Hpk + (((size_t)rpar * 2 + dir) * BB) * 1024;
  const int oj = (j >> 3) * 16 + (j & 7);
#pragma unroll
  for (int r = 0; r < 4; ++r) {
    size_t wi = (size_t)bv[r] * 1024 + oj;
    if (t < lenv[r]) {
      float gi = fac[0][r] + xgv[r][0];
      float gf = fac[1][r] + xgv[r][1];
      float gg = fac[2][r] + xgv[r][2];
      float go = fac[3][r] + xgv[r][3];
      float cn = sigmf(gf) * cstate[r] + sigmf(gi) * tanhfast(gg);
      float hn = sigmf(go) * tanhfast(cn);
      Cst[sidx[r]] = cn;
      unsigned hb = __float_as_uint(hn);
      unsigned short h16 = (unsigned short)(hb >> 16);
      unsigned short l16 =
          (unsigned short)(__float_as_uint(hn - __uint_as_float(hb & 0xffff0000u)) >> 16);
      Wb[wi] = h16;
      Wb[wi + 8] = l16;
      int ro = dir ? (lenv[r] - 1 - t) : t;
      size_t hidx = ((size_t)bv[r] * TT + ro) * DD + (size_t)dir * HH + j;
      Hhi[hidx] = h16;
      Hlo[hidx] = l16;
    } else {  // frozen row: copy state through; zero the Hseq pad slot (ro = t)
      Wb[wi] = Rb[wi];
      Wb[wi + 8] = Rb[wi + 8];
      size_t hidx = ((size_t)bv[r] * TT + t) * DD + (size_t)dir * HH + j;
      Hhi[hidx] = 0;
      Hlo[hidx] = 0;
    }
  }
}

__global__ __launch_bounds__(256) void k_bnfinal(const float* __restrict__ cs, const float* __restrict__ csq,
                                                 float* __restrict__ bnm, float* __restrict__ bni, float invN) {
  int i = blockIdx.x * 256 + threadIdx.x;
  if (i < DD) {
    float m = cs[i] * invN;
    float v = csq[i] * invN - m * m;
    bnm[i] = m;
    bni[i] = rsqrtf(v + 1e-5f);
  }
}

__global__ __launch_bounds__(128) void k_asum(float* __restrict__ alpha, const int* __restrict__ lens) {
  int b = blockIdx.x;
  int t = threadIdx.x;
  int len = lens[b];
  float v = (t < len) ? alpha[b * TT + t] : 0.f;
  float s = v;
  for (int o = 32; o > 0; o >>= 1) s += __shfl_down(s, o);
  __shared__ float sw[2];
  if ((t & 63) == 0) sw[t >> 6] = s;
  __syncthreads();
  float S = sw[0] + sw[1] + 1e-9f;
  alpha[b * TT + t] = v / S;
}

__global__ __launch_bounds__(256) void k_U(const unsigned short* __restrict__ Hhi,
                                           const unsigned short* __restrict__ Hlo,
                                           const float* __restrict__ alpha,
                                           float* __restrict__ U) {
  int b = blockIdx.x;
  int tid = threadIdx.x;
  __shared__ float al[TT];
  if (tid < TT) al[tid] = alpha[b * TT + tid];
  __syncthreads();
  float4 s = make_float4(0.f, 0.f, 0.f, 0.f);
  size_t base = (size_t)b * TT * DD + tid * 4;
#pragma unroll 4
  for (int t = 0; t < TT; ++t) {
    float a = al[t];
    ushort4 hv = *(const ushort4*)(Hhi + base + (size_t)t * DD);
    ushort4 lv = *(const ushort4*)(Hlo + base + (size_t)t * DD);
    s.x += a * (__uint_as_float((unsigned)hv.x << 16) + __uint_as_float((unsigned)lv.x << 16));
    s.y += a * (__uint_as_float((unsigned)hv.y << 16) + __uint_as_float((unsigned)lv.y << 16));
    s.z += a * (__uint_as_float((unsigned)hv.z << 16) + __uint_as_float((unsigned)lv.z << 16));
    s.w += a * (__uint_as_float((unsigned)hv.w << 16) + __uint_as_float((unsigned)lv.w << 16));
  }
  *(float4*)(U + (size_t)b * DD + tid * 4) = s;
}

__global__ __launch_bounds__(256) void k_p2a(const float* __restrict__ U,
                                             const int* __restrict__ emoI,
                                             const int* __restrict__ cauI,
                                             float* __restrict__ chunkEmb) {
  int e = blockIdx.x;
  int tid = threadIdx.x;
  __shared__ float emoS[DD];
  __shared__ float sc[NCK][16];
  const float* Ue = U + (size_t)emoI[e] * DD;
  for (int i = tid; i < DD; i += 256) emoS[i] = Ue[i];
  __syncthreads();
  int w = tid >> 6, lane = tid & 63;
  for (int p = w; p < 128; p += 4) {
    const float* y = U + (size_t)cauI[p] * DD;
    float s = 0;
    for (int d = lane; d < DD; d += 64) s += emoS[d] * y[d];
    for (int o = 32; o > 0; o >>= 1) s += __shfl_down(s, o);
    if (lane == 0) sc[p >> 4][p & 15] = s;
  }
  __syncthreads();
  if (tid < NCK) {
    float mx = -1e30f;
    for (int c = 0; c < 16; ++c) mx = fmaxf(mx, sc[tid][c]);
    float sum = 0;
    for (int c = 0; c < 16; ++c) {
      float ev = __expf(sc[tid][c] - mx);
      sc[tid][c] = ev;
      sum += ev;
    }
    float inv = 1.f / sum;
    for (int c = 0; c < 16; ++c) sc[tid][c] *= inv;
  }
  __syncthreads();
  int d = tid * 4;
  for (int nn = 0; nn < NCK; ++nn) {
    float4 s = make_float4(0.f, 0.f, 0.f, 0.f);
    for (int c = 0; c < 16; ++c) {
      float wc = sc[nn][c];
      float4 y = *(const float4*)(U + (size_t)cauI[nn * 16 + c] * DD + d);
      s.x += wc * y.x; s.y += wc * y.y; s.z += wc * y.z; s.w += wc * y.w;
    }
    *(float4*)(chunkEmb + ((size_t)e * NCK + nn) * DD + d) = s;
  }
}

__global__ __launch_bounds__(256) void k_delta2(const float* __restrict__ U,
                                                const int* __restrict__ emoI,
                                                const float* __restrict__ chunkEmb,
                                                const float* __restrict__ pos,
                                                float* __restrict__ delta2) {
  int e = blockIdx.x >> 3, nn = blockIdx.x & 7;
  int tid = threadIdx.x;
  const float* emo = U + (size_t)emoI[e] * DD;
  const float* y = chunkEmb + ((size_t)e * NCK + nn) * DD;
  __shared__ float s4[4];
  float ds = 0;
  for (int d = tid; d < DD; d += 256) {
    float df = emo[d] - y[d];
    ds += df * df;
  }
  float dist = sqrtf(blk_sum(ds, s4));
  float* out = delta2 + ((size_t)e * NCK + nn) * K3PAD;
  for (int c = tid; c < K3PAD; c += 256) {
    float v;
    if (c < 1024) v = emo[c];
    else if (c < 2048) v = y[c - 1024];
    else if (c == 2048) v = dist;
    else if (c < 3073) { int d = c - 2049; v = emo[d] * y[d]; }
    else if (c < 3123) v = pos[((size_t)e * NCK + nn) * PPP + (c - 3073)];
    else v = 0.f;
    out[c] = v;
  }
}

__global__ __launch_bounds__(256) void k_bnstats(const float* __restrict__ X,
                                                 float* __restrict__ bm, float* __restrict__ bi, int R) {
  int gid = blockIdx.x * 256 + threadIdx.x;  // NE*DD
  int e = gid >> 10, col = gid & 1023;
  const float* p = X + (size_t)e * R * DD + col;
  float s = 0, s2 = 0;
  for (int r = 0; r < R; ++r) {
    float v = p[(size_t)r * DD];
    s += v;
    s2 += v * v;
  }
  float m = s / R;
  float var = s2 / R - m * m;
  bm[gid] = m;
  bi[gid] = rsqrtf(var + 1e-5f);
}

__global__ __launch_bounds__(256) void k_out2(const float* __restrict__ h2,
                                              const float* __restrict__ bm, const float* __restrict__ bi,
                                              const float* __restrict__ Wo, const float* __restrict__ Wob,
                                              float* __restrict__ out, float* __restrict__ extraf) {
  int e = blockIdx.x >> 3, nn = blockIdx.x & 7;
  int tid = threadIdx.x;
  const float* row = h2 + ((size_t)e * NCK + nn) * DD;
  float l0 = 0, l1 = 0;
  for (int col = tid; col < DD; col += 256) {
    float h = leakyf((row[col] - bm[e * DD + col]) * bi[e * DD + col]);
    l0 += h * Wo[col];
    l1 += h * Wo[DD + col];
  }
  __shared__ float s4[4];
  l0 = blk_sum(l0, s4);
  l1 = blk_sum(l1, s4);
  if (tid == 0) {
    l0 += Wob[0];
    l1 += Wob[1];
    float mx = fmaxf(l0, l1);
    float lse = mx + logf(__expf(l0 - mx) + __expf(l1 - mx));
    out[((size_t)e * NCK + nn) * 2 + 0] = l0 - lse;
    out[((size_t)e * NCK + nn) * 2 + 1] = l1 - lse;
    extraf[e * NCK + nn] = (l1 > l0) ? 1.f : 0.f;
  }
}

__global__ __launch_bounds__(256) void k_p3(const float* __restrict__ h3,
                                            const float* __restrict__ bm, const float* __restrict__ bi,
                                            const float* __restrict__ cw, const float* __restrict__ cb,
                                            float* __restrict__ out) {
  int e = blockIdx.x >> 7, c = blockIdx.x & 127;
  int tid = threadIdx.x;
  const float* row = h3 + ((size_t)e * NCC + c) * DD;
  float l0 = 0, l1 = 0;
  for (int col = tid; col < DD; col += 256) {
    float h = leakyf((row[col] - bm[e * DD + col]) * bi[e * DD + col]);
    l0 += h * cw[col];
    l1 += h * cw[DD + col];
  }
  __shared__ float s4[4];
  l0 = blk_sum(l0, s4);
  l1 = blk_sum(l1, s4);
  if (tid == 0) {
    l0 += cb[0];
    l1 += cb[1];
    float mx = fmaxf(l0, l1);
    float lse = mx + logf(__expf(l0 - mx) + __expf(l1 - mx));
    out[((size_t)e * NCC + c) * 2 + 0] = l0 - lse;
    out[((size_t)e * NCC + c) * 2 + 1] = l1 - lse;
  }
}

__global__ __launch_bounds__(256) void k_L(const int* __restrict__ lab, float* __restrict__ out) {
  int i = blockIdx.x * 256 + threadIdx.x;  // 8192
  int e = i >> 7, c = i & 127;
  int a = lab[e * 3 + 0], b = lab[e * 3 + 1], d = lab[e * 3 + 2];
  out[i] = (a == c || b == c || d == c) ? 1.f : 0.f;
}

extern "C" void kernel_launch(void* const* d_in, const int* in_sizes, int n_in,
                              void* d_out, int out_size, void* d_ws, size_t ws_size,
                              hipStream_t stream) {
  (void)in_sizes; (void)n_in; (void)out_size; (void)ws_size;
  const float* X     = (const float*)d_in[0];
  const float* pos   = (const float*)d_in[1];
  const float* dis   = (const float*)d_in[2];
  const int*   lens  = (const int*)d_in[3];
  const int*   lab3  = (const int*)d_in[4];
  const int*   emoI  = (const int*)d_in[5];
  const int*   cauI  = (const int*)d_in[6];
  const float* Wih_f = (const float*)d_in[7];
  const float* Whh_f = (const float*)d_in[8];
  const float* bih_f = (const float*)d_in[9];
  const float* bhh_f = (const float*)d_in[10];
  const float* Wih_b = (const float*)d_in[11];
  const float* Whh_b = (const float*)d_in[12];
  const float* bih_b = (const float*)d_in[13];
  const float* bhh_b = (const float*)d_in[14];
  const float* s1w   = (const float*)d_in[15];
  const float* s1b   = (const float*)d_in[16];
  const float* s2w   = (const float*)d_in[17];
  const float* W2w   = (const float*)d_in[18];
  const float* W2b   = (const float*)d_in[19];
  const float* Wow   = (const float*)d_in[20];
  const float* Wob   = (const float*)d_in[21];
  const float* W3w   = (const float*)d_in[22];
  const float* W3b   = (const float*)d_in[23];
  const float* clsw  = (const float*)d_in[24];
  const float* clsb  = (const float*)d_in[25];
  float* ws = (float*)d_ws;
  float* out = (float*)d_out;

  unsigned short* Hhi = (unsigned short*)(ws + F_HSEQ);
  unsigned short* Hlo = Hhi + (size_t)NROWS * DD;
  unsigned short* WIHhi = (unsigned short*)(ws + F_WIH);
  unsigned short* WIHlo = WIHhi + (size_t)2 * 2048 * 1024;
  unsigned short* WHHhi = (unsigned short*)(ws + F_WHH);
  unsigned short* WHHlo = WHHhi + (size_t)2 * 2048 * 512;
  unsigned short* S1hi  = (unsigned short*)(ws + F_S1);
  unsigned short* S1lo  = S1hi + (size_t)1024 * 1024;
  unsigned short* W2hi  = (unsigned short*)(ws + F_W2);
  unsigned short* W2lo  = W2hi + (size_t)1024 * K3PAD;
  unsigned short* W3ABhi = (unsigned short*)(ws + F_W3);             // [2048][1024]
  unsigned short* W3ABlo = W3ABhi + (size_t)2048 * 1024;
  unsigned short* W3Phi  = (unsigned short*)(ws + F_W3 + 2097152ull); // [1024][KP3]
  unsigned short* W3Plo  = W3Phi + (size_t)1024 * KP3;
  unsigned short* Hpk   = (unsigned short*)(ws + F_HST);   // [2par][2dir][256][64oct][16]
  float* E3Y3 = ws + F_H2;                                  // [256][2048] (E rows 0-63 cols 0-1023; Y rows 64-191 cols 1024-2047)
  float* distb = ws + F_ALPHA;                              // dist[8192], reuses dead alpha
  int* gidx = (int*)(ws + F_GIDX);

  // zero-init read-before-write buffers (k_step zero-fills Hseq pad rows itself)
  hipMemsetAsync(ws + F_HST, 0, (size_t)(524288 + 262144) * sizeof(float), stream);  // Hpk + CST
  hipMemsetAsync(ws + F_CS, 0, (size_t)2048 * sizeof(float), stream);                // CS + CSQ
  hipMemsetAsync(ws + F_ALPHA, 0, (size_t)32768 * sizeof(float), stream);

  // weight converts (fp32 -> bf16 hi/lo, n-major = native torch layout)
  k_cvt<<<2048, 256, 0, stream>>>(Wih_f, WIHhi, WIHlo, 1024, 1024, 1024, 0);
  k_cvt<<<2048, 256, 0, stream>>>(Wih_b, WIHhi + (size_t)2048 * 1024, WIHlo + (size_t)2048 * 1024, 1024, 1024, 1024, 0);
  k_cvt<<<2048, 256, 0, stream>>>(Whh_f, WHHhi, WHHlo, 512, 512, 512, 0);
  k_cvt<<<2048, 256, 0, stream>>>(Whh_b, WHHhi + (size_t)2048 * 512, WHHlo + (size_t)2048 * 512, 512, 512, 512, 0);
  k_cvt<<<1024, 256, 0, stream>>>(s1w, S1hi, S1lo, 1024, 1024, 1024, 0);
  k_cvt<<<1024, 256, 0, stream>>>(W2w, W2hi, W2lo, 3123, K3PAD, 3123, 0);
  // W3 operand splits: AB = [W3a(cols 0..1023); W3b(cols 1024..2047)], P = [emo*y|dis|dist|ex]
  k_cvt<<<1024, 256, 0, stream>>>(W3w, W3ABhi, W3ABlo, 1024, 1024, 3173, 0);
  k_cvt<<<1024, 256, 0, stream>>>(W3w, W3ABhi + (size_t)1024 * 1024, W3ABlo + (size_t)1024 * 1024, 1024, 1024, 3173, 1024);
  k_cvtp<<<1024, 256, 0, stream>>>(W3w, W3Phi, W3Plo);
  k_biasc<<<16, 256, 0, stream>>>(bih_f, bhh_f, bih_b, bhh_b, ws + F_BIASC);
  k_gidx<<<1, 256, 0, stream>>>(emoI, cauI, gidx);

  // BiLSTM: chunked input-projection MFMA GEMMs + per-step fused recurrence (K-split)
  for (int c = 0; c < TT / CHUNK; ++c) {
    k_mf<3><<<dim3(16, 16, 2), 256, 0, stream>>>(X, nullptr, nullptr, WIHhi, WIHlo,
                                                 ws + F_BIASC, ws + F_XG,
                                                 2048, 2048, 1024, lens, c,
                                                 nullptr, nullptr, nullptr, nullptr, nullptr, nullptr,
                                                 nullptr, nullptr, nullptr, nullptr);
    for (int tt = 0; tt < CHUNK; ++tt) {
      int t = c * CHUNK + tt;
      k_step<<<dim3(256), 256, 0, stream>>>(WHHhi, WHHlo, ws + F_XG, lens,
                                            Hpk, ws + F_CST, Hhi, Hlo, t);
    }
  }

  // attention: two-pass z (BN stats, then masked-linear attention weights); A pre-split
  k_mf<1><<<dim3(256, 8), 256, 0, stream>>>(nullptr, Hhi, Hlo, S1hi, S1lo, s1b, nullptr,
                                            NROWS, 1024, 1024, nullptr, 0,
                                            nullptr, nullptr, nullptr,
                                            ws + F_CS, ws + F_CSQ, nullptr,
                                            nullptr, nullptr, nullptr, nullptr);
  k_bnfinal<<<4, 256, 0, stream>>>(ws + F_CS, ws + F_CSQ, ws + F_BNM, ws + F_BNI, 1.f / NROWS);
  k_mf<2><<<dim3(256, 8), 256, 0, stream>>>(nullptr, Hhi, Hlo, S1hi, S1lo, s1b, nullptr,
                                            NROWS, 1024, 1024, nullptr, 0,
                                            ws + F_BNM, ws + F_BNI, s2w,
                                            nullptr, nullptr, ws + F_ALPHA,
                                            nullptr, nullptr, nullptr, nullptr);
  k_asum<<<BB, TT, 0, stream>>>(ws + F_ALPHA, lens);
  k_U<<<BB, 256, 0, stream>>>(Hhi, Hlo, ws + F_ALPHA, ws + F_U);

  // phase 2 (D2/CHE overlay dead Hseq region)
  k_p2a<<<NE, 256, 0, stream>>>(ws + F_U, emoI, cauI, ws + F_CHE);
  k_delta2<<<NE * NCK, 256, 0, stream>>>(ws + F_U, emoI, ws + F_CHE, pos, ws + F_D2);
  k_mf<0><<<dim3(4, 8), 256, 0, stream>>>(ws + F_D2, nullptr, nullptr, W2hi, W2lo, W2b, ws + F_H2,
                                          512, 1024, K3PAD, nullptr, 0,
                                          nullptr, nullptr, nullptr, nullptr, nullptr, nullptr,
                                          nullptr, nullptr, nullptr, nullptr);
  k_bnstats<<<256, 256, 0, stream>>>(ws + F_H2, ws + F_BN2M, ws + F_BN2I, NCK);
  k_out2<<<NE * NCK, 256, 0, stream>>>(ws + F_H2, ws + F_BN2M, ws + F_BN2I, Wow, Wob,
                                       out, ws + F_EXTRA);

  // phase 3 restructured: h3 = emo@W3a + y@W3b + (emo*y)@W3d + dis@W3e + dist*w3c + ex*sum(W3f) + b3
  k_dist<<<NE * NCC, 256, 0, stream>>>(ws + F_U, emoI, cauI, distb);
  // E3Y3: gathered rows [emo(64) | cau(128) | pad] @ [W3a; W3b] -> [256][2048] (no bias)
  k_mf<6><<<dim3(2, 16), 256, 0, stream>>>(ws + F_U, nullptr, nullptr, W3ABhi, W3ABlo,
                                           nullptr, E3Y3, 256, 2048, 1024, nullptr, 0,
                                           nullptr, nullptr, nullptr, nullptr, nullptr, nullptr,
                                           gidx, nullptr, nullptr, nullptr);
  // P3: on-the-fly A = [emo*y | dis | dist | ex | 0], K=1088; epilogue adds E3[e] + Y3[c] + b3
  k_mf<5><<<dim3(64, 8), 256, 0, stream>>>(ws + F_U, nullptr, nullptr, W3Phi, W3Plo,
                                           E3Y3, ws + F_H3, 8192, 1024, KP3, nullptr, 0,
                                           E3Y3 + (size_t)64 * 2048 + 1024, W3b, dis,
                                           nullptr, nullptr, nullptr,
                                           emoI, cauI, distb, ws + F_EXTRA);
  k_bnstats<<<256, 256, 0, stream>>>(ws + F_H3, ws + F_BN3M, ws + F_BN3I, NCC);
  k_p3<<<NE * NCC, 256, 0, stream>>>(ws + F_H3, ws + F_BN3M, ws + F_BN3I, clsw, clsb, out + 1024);
  k_L<<<32, 256, 0, stream>>>(lab3, out + 17408);
}